// Round 13
// baseline (1675.445 us; speedup 1.0000x reference)
//
#include <hip/hip_runtime.h>
#include <cstdint>

typedef _Float16 f16x8 __attribute__((ext_vector_type(8)));
typedef float f32x4 __attribute__((ext_vector_type(4)));

#define MDIM 24000   // N*T rows
#define DDIM 1024
#define CDIM 20
#define TDIM 750
#define NBATCH 32
#define KSEL 657
#define MASKV -100.0f
#define OMEGAF 0.6f
#define SPLIT_SCALE 2048.0f
#define SPLIT_INV   4.8828125e-4f   // 2^-11 exact

// d_out element offsets (x_r, cls_x_r, cls_x_ra, x_f, cls_x_f, cls_x_fa, tcam)
#define OFF_XR     0L
#define OFF_CLSX_R 24576000L
#define OFF_CLSRA  25056000L
#define OFF_XF     25536000L
#define OFF_CLSX_F 50112000L
#define OFF_CLSFA  50592000L
#define OFF_TCAM   51072000L

#define GLOAD16(g, l) __builtin_amdgcn_global_load_lds( \
    (const __attribute__((address_space(1))) void*)(g), \
    (__attribute__((address_space(3))) void*)(l), 16, 0, 0)

#define SBAR0() __builtin_amdgcn_sched_barrier(0)

// ---------------------------------------------------------------------------
// split helpers
// ---------------------------------------------------------------------------
__global__ __launch_bounds__(256)
void split_f16(const float* __restrict__ src, long srcStride, long nrows,
               _Float16* __restrict__ D0, _Float16* __restrict__ D1) {
    const long nvec = nrows * 128;
    for (long v = (long)blockIdx.x * 256 + threadIdx.x; v < nvec; v += (long)gridDim.x * 256) {
        const long row = v >> 7;
        const int c8 = (int)(v & 127) << 3;
        const float4 x0 = *reinterpret_cast<const float4*>(&src[row * srcStride + c8]);
        const float4 x1 = *reinterpret_cast<const float4*>(&src[row * srcStride + c8 + 4]);
        float xs[8] = {x0.x, x0.y, x0.z, x0.w, x1.x, x1.y, x1.z, x1.w};
        f16x8 h0, h1;
#pragma unroll
        for (int j = 0; j < 8; ++j) {
            const _Float16 a = (_Float16)xs[j];
            h0[j] = a;
            h1[j] = (_Float16)((xs[j] - (float)a) * SPLIT_SCALE);
        }
        *reinterpret_cast<f16x8*>(&D0[v << 3]) = h0;
        *reinterpret_cast<f16x8*>(&D1[v << 3]) = h1;
    }
}

// ---------------------------------------------------------------------------
// Fused-panel split-f16 GEMM; A through LDS (r8's proven 2-barrier scheme),
// B DIRECT global->register (L2/L3-hot weights), even/odd register banks.
//   accH += A0.B0 ; accL += A0.B1 + A1.B0 ; out = accH + 2^-11*accL.
// 128x128 tile, 256 thr = 4 waves (2x2), per-wave 64x64, BK=32, 32 steps.
// r12 post-mortem: barrier A (AFTER stage+vmcnt) is the collective
// "loads landed" certificate -- it must stay. r13 attacks the measured
// bottleneck instead: LDS-read pipe (16 ds_read_b128/wave/step = 128KB per
// CU-step-pair ~ 1540cyc >> MFMA 466cyc). B never touches LDS: per-lane
// MFMA B-fragments load straight to VGPRs (wave-private => no race surface);
// LDS reads halve, LDS = 32 KiB (A only).
// vmcnt ledger (count-based, order-agnostic within pinned region):
//   per step issue A(t+1)x4 gload_lds + B(t+1)x8 reg-loads = 12 newer;
//   vmcnt(12) => A(t)+B(t) all landed. Peeled step 31: vmcnt(0).
// ---------------------------------------------------------------------------
template<int MODE>
__global__ __launch_bounds__(256, 2)
void gemm_fused_f16(const _Float16* __restrict__ A0, const _Float16* __restrict__ A1,
                    const _Float16* __restrict__ B0, const _Float16* __restrict__ B1,
                    const float* __restrict__ bias,
                    float* __restrict__ outF,
                    _Float16* __restrict__ H0, _Float16* __restrict__ H1) {
    __shared__ _Float16 sm[16384];   // 2 buf x (A0 4096 | A1 4096) = 32 KiB
    const int t = threadIdx.x;
    const int lane = t & 63;
    const int wave = t >> 6;
    const int wr = wave >> 1, wc = wave & 1;
    const int lr = lane & 15, lk = lane >> 4;
    const int wr4 = wr * 4;

    // XCD-chunked, N-fastest: 1504 = 8 XCD chunks of 188; wg = m*8 + n
    const int bid = blockIdx.x;
    const int wg = (bid & 7) * 188 + (bid >> 3);
    const long bm = (long)(wg >> 3) * 128;
    const int bn = (wg & 7) * 128;

    // A stage addressing (rows loop-invariant; k advances by +32)
    const int r_in = lane >> 2;          // 0..15
    const int c8 = (lane & 3) << 3;      // 0,8,16,24 f16
    long ra0 = bm + (wave * 2 + 0) * 16 + r_in; if (ra0 > MDIM - 1) ra0 = MDIM - 1;
    long ra1 = bm + (wave * 2 + 1) * 16 + r_in; if (ra1 > MDIM - 1) ra1 = MDIM - 1;
    const _Float16* pA0a = A0 + (ra0 << 10) + c8;
    const _Float16* pA0b = A0 + (ra1 << 10) + c8;
    const _Float16* pA1a = A1 + (ra0 << 10) + c8;
    const _Float16* pA1b = A1 + (ra1 << 10) + c8;
    const int sb0 = (wave * 2 + 0) * 512 + lane * 8;
    const int sb1 = (wave * 2 + 1) * 512 + lane * 8;

    // B direct-load addressing: uniform base + 32-bit per-lane byte offset.
    // fragment row = bn + wc*64 + ni*16 + lr (<=1023, no clamp); k = lk*8.
    uint32_t voffB[4];
#pragma unroll
    for (int ni = 0; ni < 4; ++ni)
        voffB[ni] = ((uint32_t)(bn + wc * 64 + ni * 16 + lr) << 11) + ((uint32_t)lk << 4);

#define STAGE_A(par) do { \
    _Float16* _d = sm + (par) * 8192; \
    GLOAD16(pA0a, _d + sb0);        GLOAD16(pA0b, _d + sb1); \
    GLOAD16(pA1a, _d + 4096 + sb0); GLOAD16(pA1b, _d + 4096 + sb1); \
    pA0a += 32; pA0b += 32; pA1a += 32; pA1b += 32; \
} while (0)

#define BLOAD(b0arr, b1arr) do { \
    _Pragma("unroll") for (int ni = 0; ni < 4; ++ni) { \
        b0arr[ni] = *reinterpret_cast<const f16x8*>( \
            reinterpret_cast<const char*>(B0) + voffB[ni]); \
        b1arr[ni] = *reinterpret_cast<const f16x8*>( \
            reinterpret_cast<const char*>(B1) + voffB[ni]); \
    } \
    _Pragma("unroll") for (int ni = 0; ni < 4; ++ni) voffB[ni] += 64; \
} while (0)

#define LDSA(par, sub, rb) (*(const f16x8*)&sm[(par) * 8192 + (sub) + (rb) * 512 + lr * 32 + lk * 8])

    f32x4 accH[4][4], accL[4][4];
#pragma unroll
    for (int mi = 0; mi < 4; ++mi)
#pragma unroll
        for (int ni = 0; ni < 4; ++ni) {
            accH[mi][ni] = (f32x4){0.f, 0.f, 0.f, 0.f};
            accL[mi][ni] = (f32x4){0.f, 0.f, 0.f, 0.f};
        }

    f16x8 av0[4], av1[4];
    f16x8 bE0[4], bE1[4], bO0[4], bO1[4];   // even/odd step B banks

    // one step: stage A(t+1); load B(t+1) into the OTHER bank; certify
    // tile t (vmcnt+barA); read A frags; drain; barB; MFMA with bank X.
#define STEP(par, bX0, bX1, bN0, bN1, VMC) do { \
    SBAR0(); \
    STAGE_A((par) ^ 1); \
    BLOAD(bN0, bN1); \
    SBAR0(); \
    asm volatile("s_waitcnt vmcnt(" #VMC ")" ::: "memory"); \
    SBAR0(); \
    __builtin_amdgcn_s_barrier();   /* A: all waves' tile-t A landed */ \
    SBAR0(); \
    _Pragma("unroll") for (int mi = 0; mi < 4; ++mi) av0[mi] = LDSA(par, 0,    wr4 + mi); \
    _Pragma("unroll") for (int mi = 0; mi < 4; ++mi) av1[mi] = LDSA(par, 4096, wr4 + mi); \
    asm volatile("s_waitcnt lgkmcnt(0)" ::: "memory"); \
    SBAR0(); \
    __builtin_amdgcn_s_barrier();   /* B: all waves consumed buf par */ \
    SBAR0(); \
    __builtin_amdgcn_s_setprio(1); \
    _Pragma("unroll") for (int mi = 0; mi < 4; ++mi) \
    _Pragma("unroll") for (int ni = 0; ni < 4; ++ni) \
        accH[mi][ni] = __builtin_amdgcn_mfma_f32_16x16x32_f16(av0[mi], bX0[ni], accH[mi][ni], 0, 0, 0); \
    _Pragma("unroll") for (int mi = 0; mi < 4; ++mi) \
    _Pragma("unroll") for (int ni = 0; ni < 4; ++ni) \
        accL[mi][ni] = __builtin_amdgcn_mfma_f32_16x16x32_f16(av0[mi], bX1[ni], accL[mi][ni], 0, 0, 0); \
    _Pragma("unroll") for (int mi = 0; mi < 4; ++mi) \
    _Pragma("unroll") for (int ni = 0; ni < 4; ++ni) \
        accL[mi][ni] = __builtin_amdgcn_mfma_f32_16x16x32_f16(av1[mi], bX0[ni], accL[mi][ni], 0, 0, 0); \
    __builtin_amdgcn_s_setprio(0); \
} while (0)

    // prologue: A(0) -> buf0; B(0) -> even bank  [12 VMEM in flight]
    STAGE_A(0);
    BLOAD(bE0, bE1);
    for (int it = 0; it < 15; ++it) {           // steps 0..29
        STEP(0, bE0, bE1, bO0, bO1, 12);        // even step 2it
        STEP(1, bO0, bO1, bE0, bE1, 12);        // odd step 2it+1
    }
    STEP(0, bE0, bE1, bO0, bO1, 12);            // step 30 (stages A31+B31)
    {   // peeled step 31: nothing to stage; drain everything
        SBAR0();
        asm volatile("s_waitcnt vmcnt(0)" ::: "memory");
        SBAR0();
        __builtin_amdgcn_s_barrier();
        SBAR0();
#pragma unroll
        for (int mi = 0; mi < 4; ++mi) av0[mi] = LDSA(1, 0,    wr4 + mi);
#pragma unroll
        for (int mi = 0; mi < 4; ++mi) av1[mi] = LDSA(1, 4096, wr4 + mi);
        asm volatile("s_waitcnt lgkmcnt(0)" ::: "memory");
        SBAR0();
        __builtin_amdgcn_s_setprio(1);
#pragma unroll
        for (int mi = 0; mi < 4; ++mi)
#pragma unroll
            for (int ni = 0; ni < 4; ++ni)
                accH[mi][ni] = __builtin_amdgcn_mfma_f32_16x16x32_f16(av0[mi], bO0[ni], accH[mi][ni], 0, 0, 0);
#pragma unroll
        for (int mi = 0; mi < 4; ++mi)
#pragma unroll
            for (int ni = 0; ni < 4; ++ni)
                accL[mi][ni] = __builtin_amdgcn_mfma_f32_16x16x32_f16(av0[mi], bO1[ni], accL[mi][ni], 0, 0, 0);
#pragma unroll
        for (int mi = 0; mi < 4; ++mi)
#pragma unroll
            for (int ni = 0; ni < 4; ++ni)
                accL[mi][ni] = __builtin_amdgcn_mfma_f32_16x16x32_f16(av1[mi], bO0[ni], accL[mi][ni], 0, 0, 0);
        __builtin_amdgcn_s_setprio(0);
    }

    // epilogue: C/D layout col=lane&15, row=(lane>>4)*4+r (verified r2/r4/r5)
#pragma unroll
    for (int ni = 0; ni < 4; ++ni) {
        const int col = bn + wc * 64 + ni * 16 + lr;
        const float bb = bias[col];
#pragma unroll
        for (int mi = 0; mi < 4; ++mi) {
            const long rbase = bm + wr * 64 + mi * 16 + lk * 4;
#pragma unroll
            for (int r = 0; r < 4; ++r) {
                const long row = rbase + r;
                if (row < MDIM) {
                    const float v = accH[mi][ni][r] + SPLIT_INV * accL[mi][ni][r];
                    const float hv = fmaxf(v + bb, 0.f);
                    if (MODE == 0) {
                        const _Float16 h0 = (_Float16)hv;
                        H0[row * DDIM + col] = h0;
                        H1[row * DDIM + col] = (_Float16)((hv - (float)h0) * SPLIT_SCALE);
                    } else {
                        outF[row * DDIM + col] = hv;
                    }
                }
            }
        }
    }
#undef STEP
#undef LDSA
#undef BLOAD
#undef STAGE_A
}

// ---------------------------------------------------------------------------
// cls/at heads in fp32 (precision-critical for the top-k mask), N padded to 48.
// ---------------------------------------------------------------------------
__global__ __launch_bounds__(256)
void cls_gemm_f32(const float* __restrict__ H,
                  const float* __restrict__ Wc, const float* __restrict__ bc,
                  const float* __restrict__ Wa, const float* __restrict__ ba,
                  float* __restrict__ clsx, float* __restrict__ atout) {
    __shared__ float As[16][72];
    __shared__ float Bs[16][48];
    const int tid = threadIdx.x;
    const int tx = tid & 15, ty = tid >> 4;
    const long bm = (long)blockIdx.x * 64;

    float acc[4][3];
#pragma unroll
    for (int i = 0; i < 4; ++i)
#pragma unroll
        for (int j = 0; j < 3; ++j) acc[i][j] = 0.f;

    for (int k0 = 0; k0 < DDIM; k0 += 16) {
        __syncthreads();
        {
            const int row = tid >> 2;            // 0..63
            const int kc = (tid & 3) << 2;       // 0,4,8,12
            long ar = bm + row; if (ar > MDIM - 1) ar = MDIM - 1;
            const float4 va = *reinterpret_cast<const float4*>(&H[ar * DDIM + k0 + kc]);
            As[kc + 0][row] = va.x; As[kc + 1][row] = va.y;
            As[kc + 2][row] = va.z; As[kc + 3][row] = va.w;
        }
        if (tid < 192) {
            const int n = tid >> 2;
            const int kc = (tid & 3) << 2;
            float4 w = make_float4(0.f, 0.f, 0.f, 0.f);
            if (n < 20)      w = *reinterpret_cast<const float4*>(&Wc[(long)n * DDIM + k0 + kc]);
            else if (n < 40) w = *reinterpret_cast<const float4*>(&Wa[(long)(n - 20) * DDIM + k0 + kc]);
            Bs[kc + 0][n] = w.x; Bs[kc + 1][n] = w.y;
            Bs[kc + 2][n] = w.z; Bs[kc + 3][n] = w.w;
        }
        __syncthreads();
#pragma unroll
        for (int kk = 0; kk < 16; ++kk) {
            float a[4];
            *(float4*)&a[0] = *(const float4*)&As[kk][ty * 4];
            const float b0 = Bs[kk][tx];
            const float b1 = Bs[kk][tx + 16];
            const float b2 = Bs[kk][tx + 32];
#pragma unroll
            for (int i = 0; i < 4; ++i) {
                acc[i][0] = fmaf(a[i], b0, acc[i][0]);
                acc[i][1] = fmaf(a[i], b1, acc[i][1]);
                acc[i][2] = fmaf(a[i], b2, acc[i][2]);
            }
        }
    }

#pragma unroll
    for (int j = 0; j < 3; ++j) {
        const int col = tx + 16 * j;
        const bool isC = (col < 20);
        const bool isA = (col >= 20) && (col < 40);
        const float bvv = isC ? bc[col] : (isA ? ba[col - 20] : 0.f);
#pragma unroll
        for (int i = 0; i < 4; ++i) {
            const long row = bm + ty * 4 + i;
            if (row < MDIM) {
                const float v = acc[i][j] + bvv;
                if (isC)      clsx[row * CDIM + col] = v;
                else if (isA) atout[row * CDIM + col - 20] = v;
            }
        }
    }
}

// Per (stream,n,c): bitonic sort 750 values (pad to 1024 with +inf), emit rank KSEL.
__global__ __launch_bounds__(512)
void select_kth(const float* __restrict__ clsx_r, const float* __restrict__ clsx_f,
                float* __restrict__ kth) {
    __shared__ float s[1024];
    const int b = blockIdx.x;
    const int z = b / 640;
    const int rem = b - z * 640;
    const int n = rem / CDIM;
    const int c = rem - n * CDIM;
    const float* src = (z == 0) ? clsx_r : clsx_f;
    const int tid = threadIdx.x;

    for (int i = tid; i < 1024; i += 512)
        s[i] = (i < TDIM) ? src[((long)n * TDIM + i) * CDIM + c] : 3.402823466e38f;
    __syncthreads();

    for (int k = 2; k <= 1024; k <<= 1) {
        for (int j = k >> 1; j > 0; j >>= 1) {
            for (int i = tid; i < 1024; i += 512) {
                const int ixj = i ^ j;
                if (ixj > i) {
                    const bool up = ((i & k) == 0);
                    const float x = s[i], y = s[ixj];
                    if ((x > y) == up) { s[i] = y; s[ixj] = x; }
                }
            }
            __syncthreads();
        }
    }
    if (tid == 0) kth[b] = s[KSEL - 1];
}

__global__ __launch_bounds__(256)
void final_mask(float* __restrict__ out, const float* __restrict__ kth,
                const float* __restrict__ mul_r, const float* __restrict__ mul_f) {
    const int idx = blockIdx.x * 256 + threadIdx.x;
    if (idx >= NBATCH * TDIM * CDIM) return;
    const int m = idx / CDIM;
    const int c = idx - m * CDIM;
    const int n = m / TDIM;
    const float xr  = out[OFF_CLSX_R + idx];
    const float xf  = out[OFF_CLSX_F + idx];
    const float atr = out[OFF_CLSRA + idx];
    const float atf = out[OFF_CLSFA + idx];
    const float kr = kth[n * CDIM + c];
    const float kf = kth[640 + n * CDIM + c];
    out[OFF_CLSRA + idx] = (xr > kr) ? MASKV : atr;
    out[OFF_CLSFA + idx] = (xf > kf) ? MASKV : atf;
    out[OFF_TCAM + idx]  = (xr + OMEGAF * atr) * mul_r[c] + (xf + OMEGAF * atf) * mul_f[c];
}

extern "C" void kernel_launch(void* const* d_in, const int* in_sizes, int n_in,
                              void* d_out, int out_size, void* d_ws, size_t ws_size,
                              hipStream_t stream) {
    const float* inp    = (const float*)d_in[0];
    const float* Wfc_r  = (const float*)d_in[1];
    const float* bfc_r  = (const float*)d_in[2];
    const float* Wfc1_r = (const float*)d_in[3];
    const float* bfc1_r = (const float*)d_in[4];
    const float* Wfc_f  = (const float*)d_in[5];
    const float* bfc_f  = (const float*)d_in[6];
    const float* Wfc1_f = (const float*)d_in[7];
    const float* bfc1_f = (const float*)d_in[8];
    const float* Wcls_r = (const float*)d_in[9];
    const float* bcls_r = (const float*)d_in[10];
    const float* Wcls_f = (const float*)d_in[11];
    const float* bcls_f = (const float*)d_in[12];
    const float* Wra    = (const float*)d_in[13];
    const float* bra    = (const float*)d_in[14];
    const float* Wfa    = (const float*)d_in[15];
    const float* bfa    = (const float*)d_in[16];
    const float* mul_r  = (const float*)d_in[17];
    const float* mul_f  = (const float*)d_in[18];

    float* out = (float*)d_out;
    _Float16* wsA0 = (_Float16*)d_ws;           // 24000x1024 each
    _Float16* wsA1 = wsA0 + 24576000L;
    _Float16* wsH0 = wsA1 + 24576000L;
    _Float16* wsH1 = wsH0 + 24576000L;
    _Float16* wsW  = wsH1 + 24576000L;          // 8 x 1024x1024 f16
    float* kth = (float*)(wsW + 8L * 1048576L); // 1280 f32

    dim3 blk(256);
    dim3 gg(1504);

    split_f16<<<dim3(512), blk, 0, stream>>>(Wfc_r,  1024, 1024, wsW + 0L * 1048576, wsW + 1L * 1048576);
    split_f16<<<dim3(512), blk, 0, stream>>>(Wfc1_r, 1024, 1024, wsW + 2L * 1048576, wsW + 3L * 1048576);
    split_f16<<<dim3(512), blk, 0, stream>>>(Wfc_f,  1024, 1024, wsW + 4L * 1048576, wsW + 5L * 1048576);
    split_f16<<<dim3(512), blk, 0, stream>>>(Wfc1_f, 1024, 1024, wsW + 6L * 1048576, wsW + 7L * 1048576);

    // ---- RGB stream ----
    split_f16<<<dim3(2048), blk, 0, stream>>>(inp, 2 * DDIM, MDIM, wsA0, wsA1);
    gemm_fused_f16<0><<<gg, blk, 0, stream>>>(wsA0, wsA1, wsW + 0L * 1048576, wsW + 1L * 1048576,
                                              bfc_r, nullptr, wsH0, wsH1);
    gemm_fused_f16<1><<<gg, blk, 0, stream>>>(wsH0, wsH1, wsW + 2L * 1048576, wsW + 3L * 1048576,
                                              bfc1_r, out + OFF_XR, nullptr, nullptr);
    cls_gemm_f32<<<dim3(376), blk, 0, stream>>>(out + OFF_XR, Wcls_r, bcls_r, Wra, bra,
                                                out + OFF_CLSX_R, out + OFF_CLSRA);

    // ---- Flow stream ----
    split_f16<<<dim3(2048), blk, 0, stream>>>(inp + DDIM, 2 * DDIM, MDIM, wsA0, wsA1);
    gemm_fused_f16<0><<<gg, blk, 0, stream>>>(wsA0, wsA1, wsW + 4L * 1048576, wsW + 5L * 1048576,
                                              bfc_f, nullptr, wsH0, wsH1);
    gemm_fused_f16<1><<<gg, blk, 0, stream>>>(wsH0, wsH1, wsW + 6L * 1048576, wsW + 7L * 1048576,
                                              bfc1_f, out + OFF_XF, nullptr, nullptr);
    cls_gemm_f32<<<dim3(376), blk, 0, stream>>>(out + OFF_XF, Wcls_f, bcls_f, Wfa, bfa,
                                                out + OFF_CLSX_F, out + OFF_CLSFA);

    select_kth<<<dim3(1280), dim3(512), 0, stream>>>(out + OFF_CLSX_R, out + OFF_CLSX_F, kth);
    final_mask<<<dim3((NBATCH * TDIM * CDIM + 255) / 256), blk, 0, stream>>>(out, kth, mul_r, mul_f);
}

// Round 14
// 1088.158 us; speedup vs baseline: 1.5397x; 1.5397x over previous
//
#include <hip/hip_runtime.h>
#include <cstdint>

typedef _Float16 f16x8 __attribute__((ext_vector_type(8)));
typedef float f32x4 __attribute__((ext_vector_type(4)));

#define MDIM 24000   // N*T rows
#define DDIM 1024
#define CDIM 20
#define TDIM 750
#define NBATCH 32
#define KSEL 657
#define MASKV -100.0f
#define OMEGAF 0.6f
#define SPLIT_SCALE 2048.0f
#define SPLIT_INV   4.8828125e-4f   // 2^-11 exact

// d_out element offsets (x_r, cls_x_r, cls_x_ra, x_f, cls_x_f, cls_x_fa, tcam)
#define OFF_XR     0L
#define OFF_CLSX_R 24576000L
#define OFF_CLSRA  25056000L
#define OFF_XF     25536000L
#define OFF_CLSX_F 50112000L
#define OFF_CLSFA  50592000L
#define OFF_TCAM   51072000L

#define GLOAD16(g, l) __builtin_amdgcn_global_load_lds( \
    (const __attribute__((address_space(1))) void*)(g), \
    (__attribute__((address_space(3))) void*)(l), 16, 0, 0)

#define SBAR0() __builtin_amdgcn_sched_barrier(0)

// ---------------------------------------------------------------------------
// split helpers
// ---------------------------------------------------------------------------
__global__ __launch_bounds__(256)
void split_f16(const float* __restrict__ src, long srcStride, long nrows,
               _Float16* __restrict__ D0, _Float16* __restrict__ D1) {
    const long nvec = nrows * 128;
    for (long v = (long)blockIdx.x * 256 + threadIdx.x; v < nvec; v += (long)gridDim.x * 256) {
        const long row = v >> 7;
        const int c8 = (int)(v & 127) << 3;
        const float4 x0 = *reinterpret_cast<const float4*>(&src[row * srcStride + c8]);
        const float4 x1 = *reinterpret_cast<const float4*>(&src[row * srcStride + c8 + 4]);
        float xs[8] = {x0.x, x0.y, x0.z, x0.w, x1.x, x1.y, x1.z, x1.w};
        f16x8 h0, h1;
#pragma unroll
        for (int j = 0; j < 8; ++j) {
            const _Float16 a = (_Float16)xs[j];
            h0[j] = a;
            h1[j] = (_Float16)((xs[j] - (float)a) * SPLIT_SCALE);
        }
        *reinterpret_cast<f16x8*>(&D0[v << 3]) = h0;
        *reinterpret_cast<f16x8*>(&D1[v << 3]) = h1;
    }
}

// ---------------------------------------------------------------------------
// Fused-panel split-f16 GEMM, counted-vmcnt pipeline, r8 skeleton verbatim,
// but 512 threads = 8 waves of 32x64 output each (r14: double waves/CU).
//   accH += A0.B0 ; accL += A0.B1 + A1.B0 ; out = accH + 2^-11*accL.
// 128x128 tile, BK=32, 32 steps. LDS: 2 buf x 4 tiles (128x32 f16) = 64 KiB.
// Per-wave regs: accH+accL 64 + 12 frags 48 + addr ~15 -> ~127 target;
// __launch_bounds__(512,4) => 2 blocks x 8 waves = 16 waves/CU (r8 had 8).
// r9-r13 lessons kept: both barriers are collective load-certification
// (r12); B stays in LDS via coalesced global_load_lds (r13); WRITE_SIZE is
// the spill canary (r10); all barriers/waits SBAR0-pinned (r7/r8).
// Per step t: STAGE(t+1) 4 loads -> vmcnt(4) [tile t landed] -> barrier A ->
// 12 ds_read_b128 -> lgkmcnt(0) -> barrier B -> 24 MFMA. Peel: vmcnt(0).
// ---------------------------------------------------------------------------
template<int MODE>
__global__ __launch_bounds__(512, 4)
void gemm_fused_f16(const _Float16* __restrict__ A0, const _Float16* __restrict__ A1,
                    const _Float16* __restrict__ B0, const _Float16* __restrict__ B1,
                    const float* __restrict__ bias,
                    float* __restrict__ outF,
                    _Float16* __restrict__ H0, _Float16* __restrict__ H1) {
    __shared__ _Float16 sm[32768];   // 2 x 16384 f16 (A0|A1|B0|B1 tiles)
    const int t = threadIdx.x;
    const int lane = t & 63;
    const int wave = t >> 6;         // 0..7
    const int wr = wave >> 1;        // 0..3 (M: 32 rows each)
    const int wc = wave & 1;         // 0..1 (N: 64 cols each)
    const int lr = lane & 15, lk = lane >> 4;
    const int wr2 = wr * 2, wc4 = wc * 4;

    // XCD-chunked, N-fastest: 1504 = 8 XCD chunks of 188; wg = m*8 + n
    const int bid = blockIdx.x;
    const int wg = (bid & 7) * 188 + (bid >> 3);
    const long bm = (long)(wg >> 3) * 128;
    const int bn = (wg & 7) * 128;

    // stage addressing: each wave stages ONE 16-row subtile per tile
    const int r_in = lane >> 2;          // 0..15
    const int c8 = (lane & 3) << 3;      // 0,8,16,24 f16
    long ra = bm + wave * 16 + r_in; if (ra > MDIM - 1) ra = MDIM - 1;
    const long rbn = (long)(bn + wave * 16 + r_in);
    const _Float16* pA0 = A0 + (ra << 10) + c8;
    const _Float16* pA1 = A1 + (ra << 10) + c8;
    const _Float16* pB0 = B0 + (rbn << 10) + c8;
    const _Float16* pB1 = B1 + (rbn << 10) + c8;
    const int sb = wave * 512 + lane * 8;

#define STAGE4(par) do { \
    _Float16* _d = sm + (par) * 16384; \
    GLOAD16(pA0, _d + sb); \
    GLOAD16(pA1, _d + 4096 + sb); \
    GLOAD16(pB0, _d + 8192 + sb); \
    GLOAD16(pB1, _d + 12288 + sb); \
    pA0 += 32; pA1 += 32; pB0 += 32; pB1 += 32; \
} while (0)

#define LDSF(tileoff, rb) (*(const f16x8*)&sm[cur + (tileoff) + (rb) * 512 + lr * 32 + lk * 8])

    f32x4 accH[2][4], accL[2][4];
#pragma unroll
    for (int mi = 0; mi < 2; ++mi)
#pragma unroll
        for (int ni = 0; ni < 4; ++ni) {
            accH[mi][ni] = (f32x4){0.f, 0.f, 0.f, 0.f};
            accL[mi][ni] = (f32x4){0.f, 0.f, 0.f, 0.f};
        }

    f16x8 av0[2], av1[2], bv0[4], bv1[4];

#define COMPUTE() do { \
    SBAR0(); /* pin: reads stay AFTER barrier A */ \
    _Pragma("unroll") for (int mi = 0; mi < 2; ++mi) av0[mi] = LDSF(0,     wr2 + mi); \
    _Pragma("unroll") for (int ni = 0; ni < 4; ++ni) bv0[ni] = LDSF(8192,  wc4 + ni); \
    _Pragma("unroll") for (int ni = 0; ni < 4; ++ni) bv1[ni] = LDSF(12288, wc4 + ni); \
    _Pragma("unroll") for (int mi = 0; mi < 2; ++mi) av1[mi] = LDSF(4096,  wr2 + mi); \
    asm volatile("s_waitcnt lgkmcnt(0)" ::: "memory"); \
    SBAR0(); \
    __builtin_amdgcn_s_barrier();  /* B: all waves consumed cur buf */ \
    SBAR0(); /* pin: MFMAs + next stage stay AFTER barrier B */ \
    __builtin_amdgcn_s_setprio(1); \
    _Pragma("unroll") for (int mi = 0; mi < 2; ++mi) \
    _Pragma("unroll") for (int ni = 0; ni < 4; ++ni) \
        accH[mi][ni] = __builtin_amdgcn_mfma_f32_16x16x32_f16(av0[mi], bv0[ni], accH[mi][ni], 0, 0, 0); \
    _Pragma("unroll") for (int mi = 0; mi < 2; ++mi) \
    _Pragma("unroll") for (int ni = 0; ni < 4; ++ni) \
        accL[mi][ni] = __builtin_amdgcn_mfma_f32_16x16x32_f16(av0[mi], bv1[ni], accL[mi][ni], 0, 0, 0); \
    _Pragma("unroll") for (int mi = 0; mi < 2; ++mi) \
    _Pragma("unroll") for (int ni = 0; ni < 4; ++ni) \
        accL[mi][ni] = __builtin_amdgcn_mfma_f32_16x16x32_f16(av1[mi], bv0[ni], accL[mi][ni], 0, 0, 0); \
    __builtin_amdgcn_s_setprio(0); \
} while (0)

    STAGE4(0);                       // tile 0 -> buf0 (4 loads in flight)
    for (int step = 0; step < 31; ++step) {
        const int cur = (step & 1) * 16384;
        STAGE4((step + 1) & 1);      // tile t+1 (4 newest loads)
        SBAR0();                     // pin: stage issued before the wait
        asm volatile("s_waitcnt vmcnt(4)" ::: "memory");  // tile t landed
        SBAR0();
        __builtin_amdgcn_s_barrier();                     // A: cur buf ready
        COMPUTE();
    }
    {   // peeled step 31: nothing left to stage; drain tile 31 fully
        const int cur = 16384;
        SBAR0();
        asm volatile("s_waitcnt vmcnt(0)" ::: "memory");
        SBAR0();
        __builtin_amdgcn_s_barrier();
        COMPUTE();
    }

    // epilogue: C/D layout col=lane&15, row=(lane>>4)*4+r (verified r2/r4/r5)
#pragma unroll
    for (int ni = 0; ni < 4; ++ni) {
        const int col = bn + wc * 64 + ni * 16 + lr;
        const float bb = bias[col];
#pragma unroll
        for (int mi = 0; mi < 2; ++mi) {
            const long rbase = bm + wr * 32 + mi * 16 + lk * 4;
#pragma unroll
            for (int r = 0; r < 4; ++r) {
                const long row = rbase + r;
                if (row < MDIM) {
                    const float v = accH[mi][ni][r] + SPLIT_INV * accL[mi][ni][r];
                    const float hv = fmaxf(v + bb, 0.f);
                    if (MODE == 0) {
                        const _Float16 h0 = (_Float16)hv;
                        H0[row * DDIM + col] = h0;
                        H1[row * DDIM + col] = (_Float16)((hv - (float)h0) * SPLIT_SCALE);
                    } else {
                        outF[row * DDIM + col] = hv;
                    }
                }
            }
        }
    }
#undef COMPUTE
#undef LDSF
#undef STAGE4
}

// ---------------------------------------------------------------------------
// cls/at heads in fp32 (precision-critical for the top-k mask), N padded to 48.
// M-tile 64 -> 376 blocks (fills 256 CUs better than 188).
// ---------------------------------------------------------------------------
__global__ __launch_bounds__(256)
void cls_gemm_f32(const float* __restrict__ H,
                  const float* __restrict__ Wc, const float* __restrict__ bc,
                  const float* __restrict__ Wa, const float* __restrict__ ba,
                  float* __restrict__ clsx, float* __restrict__ atout) {
    __shared__ float As[16][72];
    __shared__ float Bs[16][48];
    const int tid = threadIdx.x;
    const int tx = tid & 15, ty = tid >> 4;
    const long bm = (long)blockIdx.x * 64;

    float acc[4][3];
#pragma unroll
    for (int i = 0; i < 4; ++i)
#pragma unroll
        for (int j = 0; j < 3; ++j) acc[i][j] = 0.f;

    for (int k0 = 0; k0 < DDIM; k0 += 16) {
        __syncthreads();
        {
            const int row = tid >> 2;            // 0..63
            const int kc = (tid & 3) << 2;       // 0,4,8,12
            long ar = bm + row; if (ar > MDIM - 1) ar = MDIM - 1;
            const float4 va = *reinterpret_cast<const float4*>(&H[ar * DDIM + k0 + kc]);
            As[kc + 0][row] = va.x; As[kc + 1][row] = va.y;
            As[kc + 2][row] = va.z; As[kc + 3][row] = va.w;
        }
        if (tid < 192) {
            const int n = tid >> 2;
            const int kc = (tid & 3) << 2;
            float4 w = make_float4(0.f, 0.f, 0.f, 0.f);
            if (n < 20)      w = *reinterpret_cast<const float4*>(&Wc[(long)n * DDIM + k0 + kc]);
            else if (n < 40) w = *reinterpret_cast<const float4*>(&Wa[(long)(n - 20) * DDIM + k0 + kc]);
            Bs[kc + 0][n] = w.x; Bs[kc + 1][n] = w.y;
            Bs[kc + 2][n] = w.z; Bs[kc + 3][n] = w.w;
        }
        __syncthreads();
#pragma unroll
        for (int kk = 0; kk < 16; ++kk) {
            float a[4];
            *(float4*)&a[0] = *(const float4*)&As[kk][ty * 4];
            const float b0 = Bs[kk][tx];
            const float b1 = Bs[kk][tx + 16];
            const float b2 = Bs[kk][tx + 32];
#pragma unroll
            for (int i = 0; i < 4; ++i) {
                acc[i][0] = fmaf(a[i], b0, acc[i][0]);
                acc[i][1] = fmaf(a[i], b1, acc[i][1]);
                acc[i][2] = fmaf(a[i], b2, acc[i][2]);
            }
        }
    }

#pragma unroll
    for (int j = 0; j < 3; ++j) {
        const int col = tx + 16 * j;
        const bool isC = (col < 20);
        const bool isA = (col >= 20) && (col < 40);
        const float bvv = isC ? bc[col] : (isA ? ba[col - 20] : 0.f);
#pragma unroll
        for (int i = 0; i < 4; ++i) {
            const long row = bm + ty * 4 + i;
            if (row < MDIM) {
                const float v = acc[i][j] + bvv;
                if (isC)      clsx[row * CDIM + col] = v;
                else if (isA) atout[row * CDIM + col - 20] = v;
            }
        }
    }
}

// Per (stream,n,c): bitonic sort 750 values (pad to 1024 with +inf), emit rank KSEL.
__global__ __launch_bounds__(512)
void select_kth(const float* __restrict__ clsx_r, const float* __restrict__ clsx_f,
                float* __restrict__ kth) {
    __shared__ float s[1024];
    const int b = blockIdx.x;
    const int z = b / 640;
    const int rem = b - z * 640;
    const int n = rem / CDIM;
    const int c = rem - n * CDIM;
    const float* src = (z == 0) ? clsx_r : clsx_f;
    const int tid = threadIdx.x;

    for (int i = tid; i < 1024; i += 512)
        s[i] = (i < TDIM) ? src[((long)n * TDIM + i) * CDIM + c] : 3.402823466e38f;
    __syncthreads();

    for (int k = 2; k <= 1024; k <<= 1) {
        for (int j = k >> 1; j > 0; j >>= 1) {
            for (int i = tid; i < 1024; i += 512) {
                const int ixj = i ^ j;
                if (ixj > i) {
                    const bool up = ((i & k) == 0);
                    const float x = s[i], y = s[ixj];
                    if ((x > y) == up) { s[i] = y; s[ixj] = x; }
                }
            }
            __syncthreads();
        }
    }
    if (tid == 0) kth[b] = s[KSEL - 1];
}

__global__ __launch_bounds__(256)
void final_mask(float* __restrict__ out, const float* __restrict__ kth,
                const float* __restrict__ mul_r, const float* __restrict__ mul_f) {
    const int idx = blockIdx.x * 256 + threadIdx.x;
    if (idx >= NBATCH * TDIM * CDIM) return;
    const int m = idx / CDIM;
    const int c = idx - m * CDIM;
    const int n = m / TDIM;
    const float xr  = out[OFF_CLSX_R + idx];
    const float xf  = out[OFF_CLSX_F + idx];
    const float atr = out[OFF_CLSRA + idx];
    const float atf = out[OFF_CLSFA + idx];
    const float kr = kth[n * CDIM + c];
    const float kf = kth[640 + n * CDIM + c];
    out[OFF_CLSRA + idx] = (xr > kr) ? MASKV : atr;
    out[OFF_CLSFA + idx] = (xf > kf) ? MASKV : atf;
    out[OFF_TCAM + idx]  = (xr + OMEGAF * atr) * mul_r[c] + (xf + OMEGAF * atf) * mul_f[c];
}

extern "C" void kernel_launch(void* const* d_in, const int* in_sizes, int n_in,
                              void* d_out, int out_size, void* d_ws, size_t ws_size,
                              hipStream_t stream) {
    const float* inp    = (const float*)d_in[0];
    const float* Wfc_r  = (const float*)d_in[1];
    const float* bfc_r  = (const float*)d_in[2];
    const float* Wfc1_r = (const float*)d_in[3];
    const float* bfc1_r = (const float*)d_in[4];
    const float* Wfc_f  = (const float*)d_in[5];
    const float* bfc_f  = (const float*)d_in[6];
    const float* Wfc1_f = (const float*)d_in[7];
    const float* bfc1_f = (const float*)d_in[8];
    const float* Wcls_r = (const float*)d_in[9];
    const float* bcls_r = (const float*)d_in[10];
    const float* Wcls_f = (const float*)d_in[11];
    const float* bcls_f = (const float*)d_in[12];
    const float* Wra    = (const float*)d_in[13];
    const float* bra    = (const float*)d_in[14];
    const float* Wfa    = (const float*)d_in[15];
    const float* bfa    = (const float*)d_in[16];
    const float* mul_r  = (const float*)d_in[17];
    const float* mul_f  = (const float*)d_in[18];

    float* out = (float*)d_out;
    _Float16* wsA0 = (_Float16*)d_ws;           // 24000x1024 each
    _Float16* wsA1 = wsA0 + 24576000L;
    _Float16* wsH0 = wsA1 + 24576000L;
    _Float16* wsH1 = wsH0 + 24576000L;
    _Float16* wsW  = wsH1 + 24576000L;          // 8 x 1024x1024 f16
    float* kth = (float*)(wsW + 8L * 1048576L); // 1280 f32

    dim3 blk(256);
    dim3 gg(1504);
    dim3 bb(512);

    split_f16<<<dim3(512), blk, 0, stream>>>(Wfc_r,  1024, 1024, wsW + 0L * 1048576, wsW + 1L * 1048576);
    split_f16<<<dim3(512), blk, 0, stream>>>(Wfc1_r, 1024, 1024, wsW + 2L * 1048576, wsW + 3L * 1048576);
    split_f16<<<dim3(512), blk, 0, stream>>>(Wfc_f,  1024, 1024, wsW + 4L * 1048576, wsW + 5L * 1048576);
    split_f16<<<dim3(512), blk, 0, stream>>>(Wfc1_f, 1024, 1024, wsW + 6L * 1048576, wsW + 7L * 1048576);

    // ---- RGB stream ----
    split_f16<<<dim3(2048), blk, 0, stream>>>(inp, 2 * DDIM, MDIM, wsA0, wsA1);
    gemm_fused_f16<0><<<gg, bb, 0, stream>>>(wsA0, wsA1, wsW + 0L * 1048576, wsW + 1L * 1048576,
                                             bfc_r, nullptr, wsH0, wsH1);
    gemm_fused_f16<1><<<gg, bb, 0, stream>>>(wsH0, wsH1, wsW + 2L * 1048576, wsW + 3L * 1048576,
                                             bfc1_r, out + OFF_XR, nullptr, nullptr);
    cls_gemm_f32<<<dim3(376), blk, 0, stream>>>(out + OFF_XR, Wcls_r, bcls_r, Wra, bra,
                                                out + OFF_CLSX_R, out + OFF_CLSRA);

    // ---- Flow stream ----
    split_f16<<<dim3(2048), blk, 0, stream>>>(inp + DDIM, 2 * DDIM, MDIM, wsA0, wsA1);
    gemm_fused_f16<0><<<gg, bb, 0, stream>>>(wsA0, wsA1, wsW + 4L * 1048576, wsW + 5L * 1048576,
                                             bfc_f, nullptr, wsH0, wsH1);
    gemm_fused_f16<1><<<gg, bb, 0, stream>>>(wsH0, wsH1, wsW + 6L * 1048576, wsW + 7L * 1048576,
                                             bfc1_f, out + OFF_XF, nullptr, nullptr);
    cls_gemm_f32<<<dim3(376), blk, 0, stream>>>(out + OFF_XF, Wcls_f, bcls_f, Wfa, bfa,
                                                out + OFF_CLSX_F, out + OFF_CLSFA);

    select_kth<<<dim3(1280), dim3(512), 0, stream>>>(out + OFF_CLSX_R, out + OFF_CLSX_F, kth);
    final_mask<<<dim3((NBATCH * TDIM * CDIM + 255) / 256), blk, 0, stream>>>(out, kth, mul_r, mul_f);
}

// Round 15
// 1007.747 us; speedup vs baseline: 1.6626x; 1.0798x over previous
//
#include <hip/hip_runtime.h>
#include <cstdint>

typedef _Float16 f16x8 __attribute__((ext_vector_type(8)));
typedef float f32x4 __attribute__((ext_vector_type(4)));

#define MDIM 24000   // N*T rows
#define DDIM 1024
#define CDIM 20
#define TDIM 750
#define NBATCH 32
#define KSEL 657
#define MASKV -100.0f
#define OMEGAF 0.6f
#define SPLIT_SCALE 2048.0f
#define SPLIT_INV   4.8828125e-4f   // 2^-11 exact

// d_out element offsets (x_r, cls_x_r, cls_x_ra, x_f, cls_x_f, cls_x_fa, tcam)
#define OFF_XR     0L
#define OFF_CLSX_R 24576000L
#define OFF_CLSRA  25056000L
#define OFF_XF     25536000L
#define OFF_CLSX_F 50112000L
#define OFF_CLSFA  50592000L
#define OFF_TCAM   51072000L

#define GLOAD16(g, l) __builtin_amdgcn_global_load_lds( \
    (const __attribute__((address_space(1))) void*)(g), \
    (__attribute__((address_space(3))) void*)(l), 16, 0, 0)

#define SBAR0() __builtin_amdgcn_sched_barrier(0)

// ---------------------------------------------------------------------------
// split helpers
// ---------------------------------------------------------------------------
__global__ __launch_bounds__(256)
void split_f16(const float* __restrict__ src, long srcStride, long nrows,
               _Float16* __restrict__ D0, _Float16* __restrict__ D1) {
    const long nvec = nrows * 128;
    for (long v = (long)blockIdx.x * 256 + threadIdx.x; v < nvec; v += (long)gridDim.x * 256) {
        const long row = v >> 7;
        const int c8 = (int)(v & 127) << 3;
        const float4 x0 = *reinterpret_cast<const float4*>(&src[row * srcStride + c8]);
        const float4 x1 = *reinterpret_cast<const float4*>(&src[row * srcStride + c8 + 4]);
        float xs[8] = {x0.x, x0.y, x0.z, x0.w, x1.x, x1.y, x1.z, x1.w};
        f16x8 h0, h1;
#pragma unroll
        for (int j = 0; j < 8; ++j) {
            const _Float16 a = (_Float16)xs[j];
            h0[j] = a;
            h1[j] = (_Float16)((xs[j] - (float)a) * SPLIT_SCALE);
        }
        *reinterpret_cast<f16x8*>(&D0[v << 3]) = h0;
        *reinterpret_cast<f16x8*>(&D1[v << 3]) = h1;
    }
}

// ---------------------------------------------------------------------------
// Fused-panel split-f16 GEMM, counted-vmcnt 2-deep pipeline (r8 — validated
// local optimum; every unilateral deviation regressed: r9 P1/P2 split +2us,
// r11 serial3+3blk +37us, r12 single-barrier raced, r13 B-direct +176us,
// r14 8-wave +22us).
//   accH += A0.B0 ; accL += A0.B1 + A1.B0 ; out = accH + 2^-11*accL.
// 128x128 tile, 256 thr = 4 waves (2x2), per-wave 64x64, BK=32.
// LDS: 2 buf x 4 tiles (A0,A1,B0,B1; 128x32 f16) = 64 KiB -> 2 blocks/CU.
// Per iter t: STAGE(t+1) -> vmcnt(8) [tile t's 8 loads landed] -> barrier A
// -> 16 ds_read_b128 -> lgkmcnt(0) -> barrier B (overwrite-safe) -> 48 MFMA.
// Races: raw s_barrier is NOT a compiler fence; every barrier/waitcnt is
// bracketed with sched_barrier(0) (r7/r8 lesson). Both barriers are
// collective load-certification and cannot be removed (r12 lesson).
// ---------------------------------------------------------------------------
template<int MODE>
__global__ __launch_bounds__(256, 2)
void gemm_fused_f16(const _Float16* __restrict__ A0, const _Float16* __restrict__ A1,
                    const _Float16* __restrict__ B0, const _Float16* __restrict__ B1,
                    const float* __restrict__ bias,
                    float* __restrict__ outF,
                    _Float16* __restrict__ H0, _Float16* __restrict__ H1) {
    __shared__ _Float16 sm[32768];   // 2 x 16384 f16 (A0|A1|B0|B1 tiles)
    const int t = threadIdx.x;
    const int lane = t & 63;
    const int wave = t >> 6;
    const int wr = wave >> 1, wc = wave & 1;
    const int lr = lane & 15, lk = lane >> 4;
    const int wr4 = wr * 4, wc4 = wc * 4;

    // XCD-chunked, N-fastest: 1504 = 8 XCD chunks of 188; wg = m*8 + n
    const int bid = blockIdx.x;
    const int wg = (bid & 7) * 188 + (bid >> 3);
    const long bm = (long)(wg >> 3) * 128;
    const int bn = (wg & 7) * 128;

    // hoisted stage addressing (rows are loop-invariant; only k advances)
    const int r_in = lane >> 2;          // 0..15
    const int c8 = (lane & 3) << 3;      // 0,8,16,24 f16
    long ra0 = bm + (wave * 2 + 0) * 16 + r_in; if (ra0 > MDIM - 1) ra0 = MDIM - 1;
    long ra1 = bm + (wave * 2 + 1) * 16 + r_in; if (ra1 > MDIM - 1) ra1 = MDIM - 1;
    const long rb0 = (long)(bn + (wave * 2 + 0) * 16 + r_in);
    const long rb1 = (long)(bn + (wave * 2 + 1) * 16 + r_in);
    const _Float16* pA0a = A0 + (ra0 << 10) + c8;
    const _Float16* pA0b = A0 + (ra1 << 10) + c8;
    const _Float16* pA1a = A1 + (ra0 << 10) + c8;
    const _Float16* pA1b = A1 + (ra1 << 10) + c8;
    const _Float16* pB0a = B0 + (rb0 << 10) + c8;
    const _Float16* pB0b = B0 + (rb1 << 10) + c8;
    const _Float16* pB1a = B1 + (rb0 << 10) + c8;
    const _Float16* pB1b = B1 + (rb1 << 10) + c8;
    const int sb0 = (wave * 2 + 0) * 512 + lane * 8;
    const int sb1 = (wave * 2 + 1) * 512 + lane * 8;

#define STAGE8(par) do { \
    _Float16* _d = sm + (par) * 16384; \
    GLOAD16(pA0a, _d + sb0);         GLOAD16(pA0b, _d + sb1); \
    GLOAD16(pA1a, _d + 4096 + sb0);  GLOAD16(pA1b, _d + 4096 + sb1); \
    GLOAD16(pB0a, _d + 8192 + sb0);  GLOAD16(pB0b, _d + 8192 + sb1); \
    GLOAD16(pB1a, _d + 12288 + sb0); GLOAD16(pB1b, _d + 12288 + sb1); \
    pA0a += 32; pA0b += 32; pA1a += 32; pA1b += 32; \
    pB0a += 32; pB0b += 32; pB1a += 32; pB1b += 32; \
} while (0)

#define LDSF(tileoff, rb) (*(const f16x8*)&sm[cur + (tileoff) + (rb) * 512 + lr * 32 + lk * 8])

    f32x4 accH[4][4], accL[4][4];
#pragma unroll
    for (int mi = 0; mi < 4; ++mi)
#pragma unroll
        for (int ni = 0; ni < 4; ++ni) {
            accH[mi][ni] = (f32x4){0.f, 0.f, 0.f, 0.f};
            accL[mi][ni] = (f32x4){0.f, 0.f, 0.f, 0.f};
        }

    f16x8 av0[4], av1[4], bv0[4], bv1[4];

#define COMPUTE() do { \
    SBAR0(); /* pin: reads stay AFTER barrier A */ \
    _Pragma("unroll") for (int mi = 0; mi < 4; ++mi) av0[mi] = LDSF(0,     wr4 + mi); \
    _Pragma("unroll") for (int mi = 0; mi < 4; ++mi) av1[mi] = LDSF(4096,  wr4 + mi); \
    _Pragma("unroll") for (int ni = 0; ni < 4; ++ni) bv0[ni] = LDSF(8192,  wc4 + ni); \
    _Pragma("unroll") for (int ni = 0; ni < 4; ++ni) bv1[ni] = LDSF(12288, wc4 + ni); \
    asm volatile("s_waitcnt lgkmcnt(0)" ::: "memory"); \
    SBAR0(); \
    __builtin_amdgcn_s_barrier();  /* B: all waves consumed cur buf */ \
    SBAR0(); /* pin: MFMAs + next stage stay AFTER barrier B */ \
    __builtin_amdgcn_s_setprio(1); \
    _Pragma("unroll") for (int mi = 0; mi < 4; ++mi) \
    _Pragma("unroll") for (int ni = 0; ni < 4; ++ni) \
        accH[mi][ni] = __builtin_amdgcn_mfma_f32_16x16x32_f16(av0[mi], bv0[ni], accH[mi][ni], 0, 0, 0); \
    _Pragma("unroll") for (int mi = 0; mi < 4; ++mi) \
    _Pragma("unroll") for (int ni = 0; ni < 4; ++ni) \
        accL[mi][ni] = __builtin_amdgcn_mfma_f32_16x16x32_f16(av0[mi], bv1[ni], accL[mi][ni], 0, 0, 0); \
    _Pragma("unroll") for (int mi = 0; mi < 4; ++mi) \
    _Pragma("unroll") for (int ni = 0; ni < 4; ++ni) \
        accL[mi][ni] = __builtin_amdgcn_mfma_f32_16x16x32_f16(av1[mi], bv0[ni], accL[mi][ni], 0, 0, 0); \
    __builtin_amdgcn_s_setprio(0); \
} while (0)

    STAGE8(0);                       // tile 0 -> buf0 (8 loads in flight)
    for (int step = 0; step < 31; ++step) {
        const int cur = (step & 1) * 16384;
        STAGE8((step + 1) & 1);      // tile t+1 (8 newest loads)
        SBAR0();                     // pin: stage issued before the wait
        asm volatile("s_waitcnt vmcnt(8)" ::: "memory");  // tile t landed
        SBAR0();
        __builtin_amdgcn_s_barrier();                     // A: cur buf ready
        COMPUTE();
    }
    {   // peeled step 31: nothing left to stage; drain tile 31 fully
        const int cur = 16384;
        SBAR0();
        asm volatile("s_waitcnt vmcnt(0)" ::: "memory");
        SBAR0();
        __builtin_amdgcn_s_barrier();
        COMPUTE();
    }

    // epilogue: C/D layout col=lane&15, row=(lane>>4)*4+r (verified r2/r4/r5)
#pragma unroll
    for (int ni = 0; ni < 4; ++ni) {
        const int col = bn + wc * 64 + ni * 16 + lr;
        const float bb = bias[col];
#pragma unroll
        for (int mi = 0; mi < 4; ++mi) {
            const long rbase = bm + wr * 64 + mi * 16 + lk * 4;
#pragma unroll
            for (int r = 0; r < 4; ++r) {
                const long row = rbase + r;
                if (row < MDIM) {
                    const float v = accH[mi][ni][r] + SPLIT_INV * accL[mi][ni][r];
                    const float hv = fmaxf(v + bb, 0.f);
                    if (MODE == 0) {
                        const _Float16 h0 = (_Float16)hv;
                        H0[row * DDIM + col] = h0;
                        H1[row * DDIM + col] = (_Float16)((hv - (float)h0) * SPLIT_SCALE);
                    } else {
                        outF[row * DDIM + col] = hv;
                    }
                }
            }
        }
    }
#undef COMPUTE
#undef LDSF
#undef STAGE8
}

// ---------------------------------------------------------------------------
// cls/at heads in fp32 (precision-critical for the top-k mask), N padded to 48.
// M-tile 64 -> 376 blocks (fills 256 CUs better than 188).
// ---------------------------------------------------------------------------
__global__ __launch_bounds__(256)
void cls_gemm_f32(const float* __restrict__ H,
                  const float* __restrict__ Wc, const float* __restrict__ bc,
                  const float* __restrict__ Wa, const float* __restrict__ ba,
                  float* __restrict__ clsx, float* __restrict__ atout) {
    __shared__ float As[16][72];
    __shared__ float Bs[16][48];
    const int tid = threadIdx.x;
    const int tx = tid & 15, ty = tid >> 4;
    const long bm = (long)blockIdx.x * 64;

    float acc[4][3];
#pragma unroll
    for (int i = 0; i < 4; ++i)
#pragma unroll
        for (int j = 0; j < 3; ++j) acc[i][j] = 0.f;

    for (int k0 = 0; k0 < DDIM; k0 += 16) {
        __syncthreads();
        {
            const int row = tid >> 2;            // 0..63
            const int kc = (tid & 3) << 2;       // 0,4,8,12
            long ar = bm + row; if (ar > MDIM - 1) ar = MDIM - 1;
            const float4 va = *reinterpret_cast<const float4*>(&H[ar * DDIM + k0 + kc]);
            As[kc + 0][row] = va.x; As[kc + 1][row] = va.y;
            As[kc + 2][row] = va.z; As[kc + 3][row] = va.w;
        }
        if (tid < 192) {
            const int n = tid >> 2;
            const int kc = (tid & 3) << 2;
            float4 w = make_float4(0.f, 0.f, 0.f, 0.f);
            if (n < 20)      w = *reinterpret_cast<const float4*>(&Wc[(long)n * DDIM + k0 + kc]);
            else if (n < 40) w = *reinterpret_cast<const float4*>(&Wa[(long)(n - 20) * DDIM + k0 + kc]);
            Bs[kc + 0][n] = w.x; Bs[kc + 1][n] = w.y;
            Bs[kc + 2][n] = w.z; Bs[kc + 3][n] = w.w;
        }
        __syncthreads();
#pragma unroll
        for (int kk = 0; kk < 16; ++kk) {
            float a[4];
            *(float4*)&a[0] = *(const float4*)&As[kk][ty * 4];
            const float b0 = Bs[kk][tx];
            const float b1 = Bs[kk][tx + 16];
            const float b2 = Bs[kk][tx + 32];
#pragma unroll
            for (int i = 0; i < 4; ++i) {
                acc[i][0] = fmaf(a[i], b0, acc[i][0]);
                acc[i][1] = fmaf(a[i], b1, acc[i][1]);
                acc[i][2] = fmaf(a[i], b2, acc[i][2]);
            }
        }
    }

#pragma unroll
    for (int j = 0; j < 3; ++j) {
        const int col = tx + 16 * j;
        const bool isC = (col < 20);
        const bool isA = (col >= 20) && (col < 40);
        const float bvv = isC ? bc[col] : (isA ? ba[col - 20] : 0.f);
#pragma unroll
        for (int i = 0; i < 4; ++i) {
            const long row = bm + ty * 4 + i;
            if (row < MDIM) {
                const float v = acc[i][j] + bvv;
                if (isC)      clsx[row * CDIM + col] = v;
                else if (isA) atout[row * CDIM + col - 20] = v;
            }
        }
    }
}

// Per (stream,n,c): bitonic sort 750 values (pad to 1024 with +inf), emit rank KSEL.
__global__ __launch_bounds__(512)
void select_kth(const float* __restrict__ clsx_r, const float* __restrict__ clsx_f,
                float* __restrict__ kth) {
    __shared__ float s[1024];
    const int b = blockIdx.x;
    const int z = b / 640;
    const int rem = b - z * 640;
    const int n = rem / CDIM;
    const int c = rem - n * CDIM;
    const float* src = (z == 0) ? clsx_r : clsx_f;
    const int tid = threadIdx.x;

    for (int i = tid; i < 1024; i += 512)
        s[i] = (i < TDIM) ? src[((long)n * TDIM + i) * CDIM + c] : 3.402823466e38f;
    __syncthreads();

    for (int k = 2; k <= 1024; k <<= 1) {
        for (int j = k >> 1; j > 0; j >>= 1) {
            for (int i = tid; i < 1024; i += 512) {
                const int ixj = i ^ j;
                if (ixj > i) {
                    const bool up = ((i & k) == 0);
                    const float x = s[i], y = s[ixj];
                    if ((x > y) == up) { s[i] = y; s[ixj] = x; }
                }
            }
            __syncthreads();
        }
    }
    if (tid == 0) kth[b] = s[KSEL - 1];
}

__global__ __launch_bounds__(256)
void final_mask(float* __restrict__ out, const float* __restrict__ kth,
                const float* __restrict__ mul_r, const float* __restrict__ mul_f) {
    const int idx = blockIdx.x * 256 + threadIdx.x;
    if (idx >= NBATCH * TDIM * CDIM) return;
    const int m = idx / CDIM;
    const int c = idx - m * CDIM;
    const int n = m / TDIM;
    const float xr  = out[OFF_CLSX_R + idx];
    const float xf  = out[OFF_CLSX_F + idx];
    const float atr = out[OFF_CLSRA + idx];
    const float atf = out[OFF_CLSFA + idx];
    const float kr = kth[n * CDIM + c];
    const float kf = kth[640 + n * CDIM + c];
    out[OFF_CLSRA + idx] = (xr > kr) ? MASKV : atr;
    out[OFF_CLSFA + idx] = (xf > kf) ? MASKV : atf;
    out[OFF_TCAM + idx]  = (xr + OMEGAF * atr) * mul_r[c] + (xf + OMEGAF * atf) * mul_f[c];
}

extern "C" void kernel_launch(void* const* d_in, const int* in_sizes, int n_in,
                              void* d_out, int out_size, void* d_ws, size_t ws_size,
                              hipStream_t stream) {
    const float* inp    = (const float*)d_in[0];
    const float* Wfc_r  = (const float*)d_in[1];
    const float* bfc_r  = (const float*)d_in[2];
    const float* Wfc1_r = (const float*)d_in[3];
    const float* bfc1_r = (const float*)d_in[4];
    const float* Wfc_f  = (const float*)d_in[5];
    const float* bfc_f  = (const float*)d_in[6];
    const float* Wfc1_f = (const float*)d_in[7];
    const float* bfc1_f = (const float*)d_in[8];
    const float* Wcls_r = (const float*)d_in[9];
    const float* bcls_r = (const float*)d_in[10];
    const float* Wcls_f = (const float*)d_in[11];
    const float* bcls_f = (const float*)d_in[12];
    const float* Wra    = (const float*)d_in[13];
    const float* bra    = (const float*)d_in[14];
    const float* Wfa    = (const float*)d_in[15];
    const float* bfa    = (const float*)d_in[16];
    const float* mul_r  = (const float*)d_in[17];
    const float* mul_f  = (const float*)d_in[18];

    float* out = (float*)d_out;
    _Float16* wsA0 = (_Float16*)d_ws;           // 24000x1024 each
    _Float16* wsA1 = wsA0 + 24576000L;
    _Float16* wsH0 = wsA1 + 24576000L;
    _Float16* wsH1 = wsH0 + 24576000L;
    _Float16* wsW  = wsH1 + 24576000L;          // 8 x 1024x1024 f16
    float* kth = (float*)(wsW + 8L * 1048576L); // 1280 f32

    dim3 blk(256);
    dim3 gg(1504);

    split_f16<<<dim3(512), blk, 0, stream>>>(Wfc_r,  1024, 1024, wsW + 0L * 1048576, wsW + 1L * 1048576);
    split_f16<<<dim3(512), blk, 0, stream>>>(Wfc1_r, 1024, 1024, wsW + 2L * 1048576, wsW + 3L * 1048576);
    split_f16<<<dim3(512), blk, 0, stream>>>(Wfc_f,  1024, 1024, wsW + 4L * 1048576, wsW + 5L * 1048576);
    split_f16<<<dim3(512), blk, 0, stream>>>(Wfc1_f, 1024, 1024, wsW + 6L * 1048576, wsW + 7L * 1048576);

    // ---- RGB stream ----
    split_f16<<<dim3(2048), blk, 0, stream>>>(inp, 2 * DDIM, MDIM, wsA0, wsA1);
    gemm_fused_f16<0><<<gg, blk, 0, stream>>>(wsA0, wsA1, wsW + 0L * 1048576, wsW + 1L * 1048576,
                                              bfc_r, nullptr, wsH0, wsH1);
    gemm_fused_f16<1><<<gg, blk, 0, stream>>>(wsH0, wsH1, wsW + 2L * 1048576, wsW + 3L * 1048576,
                                              bfc1_r, out + OFF_XR, nullptr, nullptr);
    cls_gemm_f32<<<dim3(376), blk, 0, stream>>>(out + OFF_XR, Wcls_r, bcls_r, Wra, bra,
                                                out + OFF_CLSX_R, out + OFF_CLSRA);

    // ---- Flow stream ----
    split_f16<<<dim3(2048), blk, 0, stream>>>(inp + DDIM, 2 * DDIM, MDIM, wsA0, wsA1);
    gemm_fused_f16<0><<<gg, blk, 0, stream>>>(wsA0, wsA1, wsW + 4L * 1048576, wsW + 5L * 1048576,
                                              bfc_f, nullptr, wsH0, wsH1);
    gemm_fused_f16<1><<<gg, blk, 0, stream>>>(wsH0, wsH1, wsW + 6L * 1048576, wsW + 7L * 1048576,
                                              bfc1_f, out + OFF_XF, nullptr, nullptr);
    cls_gemm_f32<<<dim3(376), blk, 0, stream>>>(out + OFF_XF, Wcls_f, bcls_f, Wfa, bfa,
                                                out + OFF_CLSX_F, out + OFF_CLSFA);

    select_kth<<<dim3(1280), dim3(512), 0, stream>>>(out + OFF_CLSX_R, out + OFF_CLSX_F, kth);
    final_mask<<<dim3((NBATCH * TDIM * CDIM + 255) / 256), blk, 0, stream>>>(out, kth, mul_r, mul_f);
}

// Round 16
// 974.921 us; speedup vs baseline: 1.7185x; 1.0337x over previous
//
#include <hip/hip_runtime.h>
#include <cstdint>

typedef _Float16 f16x8 __attribute__((ext_vector_type(8)));
typedef float f32x4 __attribute__((ext_vector_type(4)));

#define MDIM 24000   // N*T rows
#define DDIM 1024
#define CDIM 20
#define TDIM 750
#define NBATCH 32
#define KSEL 657
#define MASKV -100.0f
#define OMEGAF 0.6f
#define SPLIT_SCALE 2048.0f
#define SPLIT_INV   4.8828125e-4f   // 2^-11 exact

// d_out element offsets (x_r, cls_x_r, cls_x_ra, x_f, cls_x_f, cls_x_fa, tcam)
#define OFF_XR     0L
#define OFF_CLSX_R 24576000L
#define OFF_CLSRA  25056000L
#define OFF_XF     25536000L
#define OFF_CLSX_F 50112000L
#define OFF_CLSFA  50592000L
#define OFF_TCAM   51072000L

#define GLOAD16(g, l) __builtin_amdgcn_global_load_lds( \
    (const __attribute__((address_space(1))) void*)(g), \
    (__attribute__((address_space(3))) void*)(l), 16, 0, 0)

#define SBAR0() __builtin_amdgcn_sched_barrier(0)

// ---------------------------------------------------------------------------
// split helpers
// ---------------------------------------------------------------------------
__global__ __launch_bounds__(256)
void split_f16(const float* __restrict__ src, long srcStride, long nrows,
               _Float16* __restrict__ D0, _Float16* __restrict__ D1) {
    const long nvec = nrows * 128;
    for (long v = (long)blockIdx.x * 256 + threadIdx.x; v < nvec; v += (long)gridDim.x * 256) {
        const long row = v >> 7;
        const int c8 = (int)(v & 127) << 3;
        const float4 x0 = *reinterpret_cast<const float4*>(&src[row * srcStride + c8]);
        const float4 x1 = *reinterpret_cast<const float4*>(&src[row * srcStride + c8 + 4]);
        float xs[8] = {x0.x, x0.y, x0.z, x0.w, x1.x, x1.y, x1.z, x1.w};
        f16x8 h0, h1;
#pragma unroll
        for (int j = 0; j < 8; ++j) {
            const _Float16 a = (_Float16)xs[j];
            h0[j] = a;
            h1[j] = (_Float16)((xs[j] - (float)a) * SPLIT_SCALE);
        }
        *reinterpret_cast<f16x8*>(&D0[v << 3]) = h0;
        *reinterpret_cast<f16x8*>(&D1[v << 3]) = h1;
    }
}

// Combine Wc(20x1024) + Wa(20x1024) + zero-pad into a 64x1024 split pair.
// Pad rows written as 0 EVERY call (ws is not re-poisoned; determinism).
__global__ __launch_bounds__(256)
void split_clsW(const float* __restrict__ Wc, const float* __restrict__ Wa,
                _Float16* __restrict__ D0, _Float16* __restrict__ D1) {
    const int idx = blockIdx.x * 256 + threadIdx.x;   // grid 256 -> 65536
    const int r = idx >> 10;
    const int c = idx & 1023;
    float v = 0.f;
    if (r < 20)      v = Wc[r * 1024 + c];
    else if (r < 40) v = Wa[(r - 20) * 1024 + c];
    const _Float16 h0 = (_Float16)v;
    D0[idx] = h0;
    D1[idx] = (_Float16)((v - (float)h0) * SPLIT_SCALE);
}

// ---------------------------------------------------------------------------
// Fused-panel split-f16 GEMM, counted-vmcnt 2-deep pipeline (r8 — validated
// local optimum).  accH += A0.B0 ; accL += A0.B1 + A1.B0 ;
//   out = accH + 2^-11*accL.
// 128x128 tile, 256 thr = 4 waves (2x2), per-wave 64x64, BK=32.
// MODE 0: write H0/H1 f16 splits. MODE 1: write fp32. MODE 2: write BOTH
// (layer 2: x fp32 to d_out + splits for the MFMA cls heads).
// Race discipline (r7/r8/r12): raw s_barrier is not a compiler fence ->
// every barrier/waitcnt SBAR0-bracketed; both barriers are collective
// load-certification and cannot be removed.
// ---------------------------------------------------------------------------
template<int MODE>
__global__ __launch_bounds__(256, 2)
void gemm_fused_f16(const _Float16* __restrict__ A0, const _Float16* __restrict__ A1,
                    const _Float16* __restrict__ B0, const _Float16* __restrict__ B1,
                    const float* __restrict__ bias,
                    float* __restrict__ outF,
                    _Float16* __restrict__ H0, _Float16* __restrict__ H1) {
    __shared__ _Float16 sm[32768];   // 2 x 16384 f16 (A0|A1|B0|B1 tiles)
    const int t = threadIdx.x;
    const int lane = t & 63;
    const int wave = t >> 6;
    const int wr = wave >> 1, wc = wave & 1;
    const int lr = lane & 15, lk = lane >> 4;
    const int wr4 = wr * 4, wc4 = wc * 4;

    // XCD-chunked, N-fastest: 1504 = 8 XCD chunks of 188; wg = m*8 + n
    const int bid = blockIdx.x;
    const int wg = (bid & 7) * 188 + (bid >> 3);
    const long bm = (long)(wg >> 3) * 128;
    const int bn = (wg & 7) * 128;

    // hoisted stage addressing (rows are loop-invariant; only k advances)
    const int r_in = lane >> 2;          // 0..15
    const int c8 = (lane & 3) << 3;      // 0,8,16,24 f16
    long ra0 = bm + (wave * 2 + 0) * 16 + r_in; if (ra0 > MDIM - 1) ra0 = MDIM - 1;
    long ra1 = bm + (wave * 2 + 1) * 16 + r_in; if (ra1 > MDIM - 1) ra1 = MDIM - 1;
    const long rb0 = (long)(bn + (wave * 2 + 0) * 16 + r_in);
    const long rb1 = (long)(bn + (wave * 2 + 1) * 16 + r_in);
    const _Float16* pA0a = A0 + (ra0 << 10) + c8;
    const _Float16* pA0b = A0 + (ra1 << 10) + c8;
    const _Float16* pA1a = A1 + (ra0 << 10) + c8;
    const _Float16* pA1b = A1 + (ra1 << 10) + c8;
    const _Float16* pB0a = B0 + (rb0 << 10) + c8;
    const _Float16* pB0b = B0 + (rb1 << 10) + c8;
    const _Float16* pB1a = B1 + (rb0 << 10) + c8;
    const _Float16* pB1b = B1 + (rb1 << 10) + c8;
    const int sb0 = (wave * 2 + 0) * 512 + lane * 8;
    const int sb1 = (wave * 2 + 1) * 512 + lane * 8;

#define STAGE8(par) do { \
    _Float16* _d = sm + (par) * 16384; \
    GLOAD16(pA0a, _d + sb0);         GLOAD16(pA0b, _d + sb1); \
    GLOAD16(pA1a, _d + 4096 + sb0);  GLOAD16(pA1b, _d + 4096 + sb1); \
    GLOAD16(pB0a, _d + 8192 + sb0);  GLOAD16(pB0b, _d + 8192 + sb1); \
    GLOAD16(pB1a, _d + 12288 + sb0); GLOAD16(pB1b, _d + 12288 + sb1); \
    pA0a += 32; pA0b += 32; pA1a += 32; pA1b += 32; \
    pB0a += 32; pB0b += 32; pB1a += 32; pB1b += 32; \
} while (0)

#define LDSF(tileoff, rb) (*(const f16x8*)&sm[cur + (tileoff) + (rb) * 512 + lr * 32 + lk * 8])

    f32x4 accH[4][4], accL[4][4];
#pragma unroll
    for (int mi = 0; mi < 4; ++mi)
#pragma unroll
        for (int ni = 0; ni < 4; ++ni) {
            accH[mi][ni] = (f32x4){0.f, 0.f, 0.f, 0.f};
            accL[mi][ni] = (f32x4){0.f, 0.f, 0.f, 0.f};
        }

    f16x8 av0[4], av1[4], bv0[4], bv1[4];

#define COMPUTE() do { \
    SBAR0(); /* pin: reads stay AFTER barrier A */ \
    _Pragma("unroll") for (int mi = 0; mi < 4; ++mi) av0[mi] = LDSF(0,     wr4 + mi); \
    _Pragma("unroll") for (int mi = 0; mi < 4; ++mi) av1[mi] = LDSF(4096,  wr4 + mi); \
    _Pragma("unroll") for (int ni = 0; ni < 4; ++ni) bv0[ni] = LDSF(8192,  wc4 + ni); \
    _Pragma("unroll") for (int ni = 0; ni < 4; ++ni) bv1[ni] = LDSF(12288, wc4 + ni); \
    asm volatile("s_waitcnt lgkmcnt(0)" ::: "memory"); \
    SBAR0(); \
    __builtin_amdgcn_s_barrier();  /* B: all waves consumed cur buf */ \
    SBAR0(); /* pin: MFMAs + next stage stay AFTER barrier B */ \
    __builtin_amdgcn_s_setprio(1); \
    _Pragma("unroll") for (int mi = 0; mi < 4; ++mi) \
    _Pragma("unroll") for (int ni = 0; ni < 4; ++ni) \
        accH[mi][ni] = __builtin_amdgcn_mfma_f32_16x16x32_f16(av0[mi], bv0[ni], accH[mi][ni], 0, 0, 0); \
    _Pragma("unroll") for (int mi = 0; mi < 4; ++mi) \
    _Pragma("unroll") for (int ni = 0; ni < 4; ++ni) \
        accL[mi][ni] = __builtin_amdgcn_mfma_f32_16x16x32_f16(av0[mi], bv1[ni], accL[mi][ni], 0, 0, 0); \
    _Pragma("unroll") for (int mi = 0; mi < 4; ++mi) \
    _Pragma("unroll") for (int ni = 0; ni < 4; ++ni) \
        accL[mi][ni] = __builtin_amdgcn_mfma_f32_16x16x32_f16(av1[mi], bv0[ni], accL[mi][ni], 0, 0, 0); \
    __builtin_amdgcn_s_setprio(0); \
} while (0)

    STAGE8(0);                       // tile 0 -> buf0 (8 loads in flight)
    for (int step = 0; step < 31; ++step) {
        const int cur = (step & 1) * 16384;
        STAGE8((step + 1) & 1);      // tile t+1 (8 newest loads)
        SBAR0();                     // pin: stage issued before the wait
        asm volatile("s_waitcnt vmcnt(8)" ::: "memory");  // tile t landed
        SBAR0();
        __builtin_amdgcn_s_barrier();                     // A: cur buf ready
        COMPUTE();
    }
    {   // peeled step 31: nothing left to stage; drain tile 31 fully
        const int cur = 16384;
        SBAR0();
        asm volatile("s_waitcnt vmcnt(0)" ::: "memory");
        SBAR0();
        __builtin_amdgcn_s_barrier();
        COMPUTE();
    }

    // epilogue: C/D layout col=lane&15, row=(lane>>4)*4+r (verified r2/r4/r5)
#pragma unroll
    for (int ni = 0; ni < 4; ++ni) {
        const int col = bn + wc * 64 + ni * 16 + lr;
        const float bb = bias[col];
#pragma unroll
        for (int mi = 0; mi < 4; ++mi) {
            const long rbase = bm + wr * 64 + mi * 16 + lk * 4;
#pragma unroll
            for (int r = 0; r < 4; ++r) {
                const long row = rbase + r;
                if (row < MDIM) {
                    const float v = accH[mi][ni][r] + SPLIT_INV * accL[mi][ni][r];
                    const float hv = fmaxf(v + bb, 0.f);
                    if (MODE == 1 || MODE == 2) outF[row * DDIM + col] = hv;
                    if (MODE == 0 || MODE == 2) {
                        const _Float16 h0 = (_Float16)hv;
                        H0[row * DDIM + col] = h0;
                        H1[row * DDIM + col] = (_Float16)((hv - (float)h0) * SPLIT_SCALE);
                    }
                }
            }
        }
    }
#undef COMPUTE
#undef LDSF
#undef STAGE8
}

// ---------------------------------------------------------------------------
// cls/at heads via split-f16 MFMA (precision: 3-panel rel err ~2^-20 <<
// mask budget ~2^-7.3).  A = x splits [24000][1024]; B = combined W splits
// [64][1024] (rows 0..19 Wc, 20..39 Wa, 40..63 zero).
// Tile 64 rows x 48 cols; 375 blocks (24000 = 64*375, no clamping);
// 256 thr = 4 waves, wave w owns rows w*16..w*16+15, all 48 cols.
// Same r8 skeleton: STAGE(t+1)[4] -> vmcnt(4) -> barA -> 8 ds_read ->
// lgkmcnt(0) -> barB -> 9 MFMA.  LDS 2 x 16 KiB.
// ---------------------------------------------------------------------------
__global__ __launch_bounds__(256, 2)
void cls_mfma_f16(const _Float16* __restrict__ A0, const _Float16* __restrict__ A1,
                  const _Float16* __restrict__ B0, const _Float16* __restrict__ B1,
                  const float* __restrict__ bc, const float* __restrict__ ba,
                  float* __restrict__ clsx, float* __restrict__ atout) {
    __shared__ _Float16 sm[16384];   // 2 buf x (A0 2048|A1 2048|B0 2048|B1 2048)
    const int t = threadIdx.x;
    const int lane = t & 63;
    const int wave = t >> 6;         // 0..3
    const int lr = lane & 15, lk = lane >> 4;
    const long bm = (long)blockIdx.x * 64;

    const int r_in = lane >> 2;          // 0..15
    const int c8 = (lane & 3) << 3;      // 0,8,16,24 f16
    const long raA = bm + wave * 16 + r_in;          // < 24000 exactly
    const long raB = (long)(wave * 16 + r_in);       // 0..63
    const _Float16* pA0 = A0 + (raA << 10) + c8;
    const _Float16* pA1 = A1 + (raA << 10) + c8;
    const _Float16* pB0 = B0 + (raB << 10) + c8;
    const _Float16* pB1 = B1 + (raB << 10) + c8;
    const int sb = wave * 512 + lane * 8;

#define CSTAGE(par) do { \
    _Float16* _d = sm + (par) * 8192; \
    GLOAD16(pA0, _d + sb); \
    GLOAD16(pA1, _d + 2048 + sb); \
    GLOAD16(pB0, _d + 4096 + sb); \
    GLOAD16(pB1, _d + 6144 + sb); \
    pA0 += 32; pA1 += 32; pB0 += 32; pB1 += 32; \
} while (0)

#define CLDS(tileoff, rb) (*(const f16x8*)&sm[cur + (tileoff) + (rb) * 512 + lr * 32 + lk * 8])

    f32x4 accH[3], accL[3];
#pragma unroll
    for (int ni = 0; ni < 3; ++ni) {
        accH[ni] = (f32x4){0.f, 0.f, 0.f, 0.f};
        accL[ni] = (f32x4){0.f, 0.f, 0.f, 0.f};
    }
    f16x8 av0, av1, bv0[3], bv1[3];

#define CCOMPUTE() do { \
    SBAR0(); \
    av0 = CLDS(0, wave); \
    av1 = CLDS(2048, wave); \
    _Pragma("unroll") for (int ni = 0; ni < 3; ++ni) bv0[ni] = CLDS(4096, ni); \
    _Pragma("unroll") for (int ni = 0; ni < 3; ++ni) bv1[ni] = CLDS(6144, ni); \
    asm volatile("s_waitcnt lgkmcnt(0)" ::: "memory"); \
    SBAR0(); \
    __builtin_amdgcn_s_barrier(); \
    SBAR0(); \
    _Pragma("unroll") for (int ni = 0; ni < 3; ++ni) \
        accH[ni] = __builtin_amdgcn_mfma_f32_16x16x32_f16(av0, bv0[ni], accH[ni], 0, 0, 0); \
    _Pragma("unroll") for (int ni = 0; ni < 3; ++ni) \
        accL[ni] = __builtin_amdgcn_mfma_f32_16x16x32_f16(av0, bv1[ni], accL[ni], 0, 0, 0); \
    _Pragma("unroll") for (int ni = 0; ni < 3; ++ni) \
        accL[ni] = __builtin_amdgcn_mfma_f32_16x16x32_f16(av1, bv0[ni], accL[ni], 0, 0, 0); \
} while (0)

    CSTAGE(0);
    for (int step = 0; step < 31; ++step) {
        const int cur = (step & 1) * 8192;
        CSTAGE((step + 1) & 1);
        SBAR0();
        asm volatile("s_waitcnt vmcnt(4)" ::: "memory");
        SBAR0();
        __builtin_amdgcn_s_barrier();
        CCOMPUTE();
    }
    {
        const int cur = 8192;
        SBAR0();
        asm volatile("s_waitcnt vmcnt(0)" ::: "memory");
        SBAR0();
        __builtin_amdgcn_s_barrier();
        CCOMPUTE();
    }

#pragma unroll
    for (int ni = 0; ni < 3; ++ni) {
        const int col = ni * 16 + lr;                 // 0..47
        const float bvv = (col < 20) ? bc[col] : ((col < 40) ? ba[col - 20] : 0.f);
#pragma unroll
        for (int r = 0; r < 4; ++r) {
            const long row = bm + wave * 16 + lk * 4 + r;
            const float v = accH[ni][r] + SPLIT_INV * accL[ni][r] + bvv;
            if (col < 20)      clsx[row * CDIM + col] = v;
            else if (col < 40) atout[row * CDIM + col - 20] = v;
        }
    }
#undef CCOMPUTE
#undef CLDS
#undef CSTAGE
}

// ---------------------------------------------------------------------------
// Exact rank-KSEL selection per (stream,n,c) via 4-pass LDS radix-select on
// sortable-uint keys.  Replaces the 55-phase bitonic.  Exact: finds v with
// count(u<v) < KSEL <= count(u<=v)  ==  sorted[KSEL-1].
// ---------------------------------------------------------------------------
__global__ __launch_bounds__(256)
void select_kth(const float* __restrict__ clsx_r, const float* __restrict__ clsx_f,
                float* __restrict__ kth) {
    __shared__ uint32_t su[TDIM];
    __shared__ uint32_t hist[256];
    __shared__ uint32_t s_prefix, s_rank, s_mask;
    const int b = blockIdx.x;
    const int z = b / 640;
    const int rem = b - z * 640;
    const int n = rem / CDIM;
    const int c = rem - n * CDIM;
    const float* src = (z == 0) ? clsx_r : clsx_f;
    const int tid = threadIdx.x;

    for (int i = tid; i < TDIM; i += 256) {
        const uint32_t bits = __float_as_uint(src[((long)n * TDIM + i) * CDIM + c]);
        su[i] = (bits & 0x80000000u) ? ~bits : (bits | 0x80000000u);
    }
    if (tid == 0) { s_prefix = 0; s_rank = KSEL; s_mask = 0; }
    __syncthreads();

#pragma unroll
    for (int pass = 0; pass < 4; ++pass) {
        const int shift = 24 - pass * 8;
        if (tid < 256) hist[tid] = 0;
        __syncthreads();
        const uint32_t pfx = s_prefix, msk = s_mask;
        for (int i = tid; i < TDIM; i += 256) {
            const uint32_t u = su[i];
            if ((u & msk) == pfx) atomicAdd(&hist[(u >> shift) & 255u], 1u);
        }
        __syncthreads();
        if (tid == 0) {
            uint32_t cum = 0;
            for (uint32_t d = 0; d < 256; ++d) {
                const uint32_t nc = cum + hist[d];
                if (nc >= s_rank) { s_prefix |= d << shift; s_rank -= cum; break; }
                cum = nc;
            }
            s_mask |= 0xffu << shift;
        }
        __syncthreads();
    }
    if (tid == 0) {
        const uint32_t u = s_prefix;
        kth[b] = (u & 0x80000000u) ? __uint_as_float(u ^ 0x80000000u)
                                   : __uint_as_float(~u);
    }
}

__global__ __launch_bounds__(256)
void final_mask(float* __restrict__ out, const float* __restrict__ kth,
                const float* __restrict__ mul_r, const float* __restrict__ mul_f) {
    const int idx = blockIdx.x * 256 + threadIdx.x;
    if (idx >= NBATCH * TDIM * CDIM) return;
    const int m = idx / CDIM;
    const int c = idx - m * CDIM;
    const int n = m / TDIM;
    const float xr  = out[OFF_CLSX_R + idx];
    const float xf  = out[OFF_CLSX_F + idx];
    const float atr = out[OFF_CLSRA + idx];
    const float atf = out[OFF_CLSFA + idx];
    const float kr = kth[n * CDIM + c];
    const float kf = kth[640 + n * CDIM + c];
    out[OFF_CLSRA + idx] = (xr > kr) ? MASKV : atr;
    out[OFF_CLSFA + idx] = (xf > kf) ? MASKV : atf;
    out[OFF_TCAM + idx]  = (xr + OMEGAF * atr) * mul_r[c] + (xf + OMEGAF * atf) * mul_f[c];
}

extern "C" void kernel_launch(void* const* d_in, const int* in_sizes, int n_in,
                              void* d_out, int out_size, void* d_ws, size_t ws_size,
                              hipStream_t stream) {
    const float* inp    = (const float*)d_in[0];
    const float* Wfc_r  = (const float*)d_in[1];
    const float* bfc_r  = (const float*)d_in[2];
    const float* Wfc1_r = (const float*)d_in[3];
    const float* bfc1_r = (const float*)d_in[4];
    const float* Wfc_f  = (const float*)d_in[5];
    const float* bfc_f  = (const float*)d_in[6];
    const float* Wfc1_f = (const float*)d_in[7];
    const float* bfc1_f = (const float*)d_in[8];
    const float* Wcls_r = (const float*)d_in[9];
    const float* bcls_r = (const float*)d_in[10];
    const float* Wcls_f = (const float*)d_in[11];
    const float* bcls_f = (const float*)d_in[12];
    const float* Wra    = (const float*)d_in[13];
    const float* bra    = (const float*)d_in[14];
    const float* Wfa    = (const float*)d_in[15];
    const float* bfa    = (const float*)d_in[16];
    const float* mul_r  = (const float*)d_in[17];
    const float* mul_f  = (const float*)d_in[18];

    float* out = (float*)d_out;
    _Float16* wsA0 = (_Float16*)d_ws;            // 24000x1024 each
    _Float16* wsA1 = wsA0 + 24576000L;
    _Float16* wsH0 = wsA1 + 24576000L;
    _Float16* wsH1 = wsH0 + 24576000L;
    _Float16* wsW  = wsH1 + 24576000L;           // 8 x 1024x1024 f16
    _Float16* wsWc = wsW + 8L * 1048576L;        // 4 x 64x1024 f16 (cls W splits)
    float* kth = (float*)(wsWc + 4L * 65536L);   // 1280 f32

    dim3 blk(256);
    dim3 gg(1504);

    split_f16<<<dim3(512), blk, 0, stream>>>(Wfc_r,  1024, 1024, wsW + 0L * 1048576, wsW + 1L * 1048576);
    split_f16<<<dim3(512), blk, 0, stream>>>(Wfc1_r, 1024, 1024, wsW + 2L * 1048576, wsW + 3L * 1048576);
    split_f16<<<dim3(512), blk, 0, stream>>>(Wfc_f,  1024, 1024, wsW + 4L * 1048576, wsW + 5L * 1048576);
    split_f16<<<dim3(512), blk, 0, stream>>>(Wfc1_f, 1024, 1024, wsW + 6L * 1048576, wsW + 7L * 1048576);
    split_clsW<<<dim3(256), blk, 0, stream>>>(Wcls_r, Wra, wsWc + 0L * 65536, wsWc + 1L * 65536);
    split_clsW<<<dim3(256), blk, 0, stream>>>(Wcls_f, Wfa, wsWc + 2L * 65536, wsWc + 3L * 65536);

    // ---- RGB stream ----
    split_f16<<<dim3(2048), blk, 0, stream>>>(inp, 2 * DDIM, MDIM, wsA0, wsA1);
    gemm_fused_f16<0><<<gg, blk, 0, stream>>>(wsA0, wsA1, wsW + 0L * 1048576, wsW + 1L * 1048576,
                                              bfc_r, nullptr, wsH0, wsH1);
    gemm_fused_f16<2><<<gg, blk, 0, stream>>>(wsH0, wsH1, wsW + 2L * 1048576, wsW + 3L * 1048576,
                                              bfc1_r, out + OFF_XR, wsA0, wsA1);
    cls_mfma_f16<<<dim3(375), blk, 0, stream>>>(wsA0, wsA1, wsWc + 0L * 65536, wsWc + 1L * 65536,
                                                bcls_r, bra, out + OFF_CLSX_R, out + OFF_CLSRA);

    // ---- Flow stream ----
    split_f16<<<dim3(2048), blk, 0, stream>>>(inp + DDIM, 2 * DDIM, MDIM, wsA0, wsA1);
    gemm_fused_f16<0><<<gg, blk, 0, stream>>>(wsA0, wsA1, wsW + 4L * 1048576, wsW + 5L * 1048576,
                                              bfc_f, nullptr, wsH0, wsH1);
    gemm_fused_f16<2><<<gg, blk, 0, stream>>>(wsH0, wsH1, wsW + 6L * 1048576, wsW + 7L * 1048576,
                                              bfc1_f, out + OFF_XF, wsA0, wsA1);
    cls_mfma_f16<<<dim3(375), blk, 0, stream>>>(wsA0, wsA1, wsWc + 2L * 65536, wsWc + 3L * 65536,
                                                bcls_f, bfa, out + OFF_CLSX_F, out + OFF_CLSFA);

    select_kth<<<dim3(1280), blk, 0, stream>>>(out + OFF_CLSX_R, out + OFF_CLSX_F, kth);
    final_mask<<<dim3((NBATCH * TDIM * CDIM + 255) / 256), blk, 0, stream>>>(out, kth, mul_r, mul_f);
}

// Round 17
// 901.522 us; speedup vs baseline: 1.8585x; 1.0814x over previous
//
#include <hip/hip_runtime.h>
#include <cstdint>

typedef _Float16 f16x8 __attribute__((ext_vector_type(8)));
typedef float f32x4 __attribute__((ext_vector_type(4)));

#define MDIM 24000   // N*T rows
#define DDIM 1024
#define CDIM 20
#define TDIM 750
#define NBATCH 32
#define KSEL 657
#define MASKV -100.0f
#define OMEGAF 0.6f
#define SPLIT_SCALE 2048.0f
#define SPLIT_INV   4.8828125e-4f   // 2^-11 exact

// d_out element offsets (x_r, cls_x_r, cls_x_ra, x_f, cls_x_f, cls_x_fa, tcam)
#define OFF_XR     0L
#define OFF_CLSX_R 24576000L
#define OFF_CLSRA  25056000L
#define OFF_XF     25536000L
#define OFF_CLSX_F 50112000L
#define OFF_CLSFA  50592000L
#define OFF_TCAM   51072000L

#define GLOAD16(g, l) __builtin_amdgcn_global_load_lds( \
    (const __attribute__((address_space(1))) void*)(g), \
    (__attribute__((address_space(3))) void*)(l), 16, 0, 0)

#define SBAR0() __builtin_amdgcn_sched_barrier(0)

// ---------------------------------------------------------------------------
// split helpers
// ---------------------------------------------------------------------------
__global__ __launch_bounds__(256)
void split_f16(const float* __restrict__ src, long srcStride, long nrows,
               _Float16* __restrict__ D0, _Float16* __restrict__ D1) {
    const long nvec = nrows * 128;
    for (long v = (long)blockIdx.x * 256 + threadIdx.x; v < nvec; v += (long)gridDim.x * 256) {
        const long row = v >> 7;
        const int c8 = (int)(v & 127) << 3;
        const float4 x0 = *reinterpret_cast<const float4*>(&src[row * srcStride + c8]);
        const float4 x1 = *reinterpret_cast<const float4*>(&src[row * srcStride + c8 + 4]);
        float xs[8] = {x0.x, x0.y, x0.z, x0.w, x1.x, x1.y, x1.z, x1.w};
        f16x8 h0, h1;
#pragma unroll
        for (int j = 0; j < 8; ++j) {
            const _Float16 a = (_Float16)xs[j];
            h0[j] = a;
            h1[j] = (_Float16)((xs[j] - (float)a) * SPLIT_SCALE);
        }
        *reinterpret_cast<f16x8*>(&D0[v << 3]) = h0;
        *reinterpret_cast<f16x8*>(&D1[v << 3]) = h1;
    }
}

// All four 1024x1024 FC-weight splits in ONE launch: weight i <- blockIdx>>9,
// outputs at Dbase + 2i*1M (h0) / (2i+1)*1M (h1).
__global__ __launch_bounds__(256)
void split_w4(const float* __restrict__ W0, const float* __restrict__ W1,
              const float* __restrict__ W2, const float* __restrict__ W3,
              _Float16* __restrict__ Dbase) {
    const int wi = blockIdx.x >> 9;                 // 0..3
    const int bid = blockIdx.x & 511;
    const float* __restrict__ src = (wi == 0) ? W0 : (wi == 1) ? W1 : (wi == 2) ? W2 : W3;
    _Float16* __restrict__ D0 = Dbase + (long)(2 * wi) * 1048576L;
    _Float16* __restrict__ D1 = D0 + 1048576L;
    for (long v = (long)bid * 256 + threadIdx.x; v < 131072L; v += 512L * 256) {
        const long row = v >> 7;
        const int c8 = (int)(v & 127) << 3;
        const float4 x0 = *reinterpret_cast<const float4*>(&src[row * 1024 + c8]);
        const float4 x1 = *reinterpret_cast<const float4*>(&src[row * 1024 + c8 + 4]);
        float xs[8] = {x0.x, x0.y, x0.z, x0.w, x1.x, x1.y, x1.z, x1.w};
        f16x8 h0, h1;
#pragma unroll
        for (int j = 0; j < 8; ++j) {
            const _Float16 a = (_Float16)xs[j];
            h0[j] = a;
            h1[j] = (_Float16)((xs[j] - (float)a) * SPLIT_SCALE);
        }
        *reinterpret_cast<f16x8*>(&D0[v << 3]) = h0;
        *reinterpret_cast<f16x8*>(&D1[v << 3]) = h1;
    }
}

// Both streams' cls-W combines in ONE launch (z = blockIdx>>8):
// (Wc|Wa|zero-pad) 64x1024 -> split pair at Dbase + z*2*65536.
// Pad rows written as 0 EVERY call (ws not re-poisoned; determinism).
__global__ __launch_bounds__(256)
void split_clsW2(const float* __restrict__ Wc_r, const float* __restrict__ Wa_r,
                 const float* __restrict__ Wc_f, const float* __restrict__ Wa_f,
                 _Float16* __restrict__ Dbase) {
    const int z = blockIdx.x >> 8;                  // 0..1
    const int idx = (blockIdx.x & 255) * 256 + threadIdx.x;   // 0..65535
    const float* __restrict__ Wc = z ? Wc_f : Wc_r;
    const float* __restrict__ Wa = z ? Wa_f : Wa_r;
    _Float16* __restrict__ D0 = Dbase + (long)z * 131072L;
    _Float16* __restrict__ D1 = D0 + 65536L;
    const int r = idx >> 10;
    const int c = idx & 1023;
    float v = 0.f;
    if (r < 20)      v = Wc[r * 1024 + c];
    else if (r < 40) v = Wa[(r - 20) * 1024 + c];
    const _Float16 h0 = (_Float16)v;
    D0[idx] = h0;
    D1[idx] = (_Float16)((v - (float)h0) * SPLIT_SCALE);
}

// ---------------------------------------------------------------------------
// Fused-panel split-f16 GEMM, counted-vmcnt 2-deep pipeline (r8 — validated
// local optimum; rounds 9-14 measured every structural alternative worse).
//   accH += A0.B0 ; accL += A0.B1 + A1.B0 ; out = accH + 2^-11*accL.
// 128x128 tile, 256 thr = 4 waves (2x2), per-wave 64x64, BK=32.
// MODE 0: write H0/H1 f16 splits. MODE 1: write fp32. MODE 2: write BOTH.
// Race discipline (r7/r8/r12): raw s_barrier is not a compiler fence ->
// every barrier/waitcnt SBAR0-bracketed; both barriers are collective
// load-certification and cannot be removed.
// ---------------------------------------------------------------------------
template<int MODE>
__global__ __launch_bounds__(256, 2)
void gemm_fused_f16(const _Float16* __restrict__ A0, const _Float16* __restrict__ A1,
                    const _Float16* __restrict__ B0, const _Float16* __restrict__ B1,
                    const float* __restrict__ bias,
                    float* __restrict__ outF,
                    _Float16* __restrict__ H0, _Float16* __restrict__ H1) {
    __shared__ _Float16 sm[32768];   // 2 x 16384 f16 (A0|A1|B0|B1 tiles)
    const int t = threadIdx.x;
    const int lane = t & 63;
    const int wave = t >> 6;
    const int wr = wave >> 1, wc = wave & 1;
    const int lr = lane & 15, lk = lane >> 4;
    const int wr4 = wr * 4, wc4 = wc * 4;

    // XCD-chunked, N-fastest: 1504 = 8 XCD chunks of 188; wg = m*8 + n
    const int bid = blockIdx.x;
    const int wg = (bid & 7) * 188 + (bid >> 3);
    const long bm = (long)(wg >> 3) * 128;
    const int bn = (wg & 7) * 128;

    // hoisted stage addressing (rows are loop-invariant; only k advances)
    const int r_in = lane >> 2;          // 0..15
    const int c8 = (lane & 3) << 3;      // 0,8,16,24 f16
    long ra0 = bm + (wave * 2 + 0) * 16 + r_in; if (ra0 > MDIM - 1) ra0 = MDIM - 1;
    long ra1 = bm + (wave * 2 + 1) * 16 + r_in; if (ra1 > MDIM - 1) ra1 = MDIM - 1;
    const long rb0 = (long)(bn + (wave * 2 + 0) * 16 + r_in);
    const long rb1 = (long)(bn + (wave * 2 + 1) * 16 + r_in);
    const _Float16* pA0a = A0 + (ra0 << 10) + c8;
    const _Float16* pA0b = A0 + (ra1 << 10) + c8;
    const _Float16* pA1a = A1 + (ra0 << 10) + c8;
    const _Float16* pA1b = A1 + (ra1 << 10) + c8;
    const _Float16* pB0a = B0 + (rb0 << 10) + c8;
    const _Float16* pB0b = B0 + (rb1 << 10) + c8;
    const _Float16* pB1a = B1 + (rb0 << 10) + c8;
    const _Float16* pB1b = B1 + (rb1 << 10) + c8;
    const int sb0 = (wave * 2 + 0) * 512 + lane * 8;
    const int sb1 = (wave * 2 + 1) * 512 + lane * 8;

#define STAGE8(par) do { \
    _Float16* _d = sm + (par) * 16384; \
    GLOAD16(pA0a, _d + sb0);         GLOAD16(pA0b, _d + sb1); \
    GLOAD16(pA1a, _d + 4096 + sb0);  GLOAD16(pA1b, _d + 4096 + sb1); \
    GLOAD16(pB0a, _d + 8192 + sb0);  GLOAD16(pB0b, _d + 8192 + sb1); \
    GLOAD16(pB1a, _d + 12288 + sb0); GLOAD16(pB1b, _d + 12288 + sb1); \
    pA0a += 32; pA0b += 32; pA1a += 32; pA1b += 32; \
    pB0a += 32; pB0b += 32; pB1a += 32; pB1b += 32; \
} while (0)

#define LDSF(tileoff, rb) (*(const f16x8*)&sm[cur + (tileoff) + (rb) * 512 + lr * 32 + lk * 8])

    f32x4 accH[4][4], accL[4][4];
#pragma unroll
    for (int mi = 0; mi < 4; ++mi)
#pragma unroll
        for (int ni = 0; ni < 4; ++ni) {
            accH[mi][ni] = (f32x4){0.f, 0.f, 0.f, 0.f};
            accL[mi][ni] = (f32x4){0.f, 0.f, 0.f, 0.f};
        }

    f16x8 av0[4], av1[4], bv0[4], bv1[4];

#define COMPUTE() do { \
    SBAR0(); /* pin: reads stay AFTER barrier A */ \
    _Pragma("unroll") for (int mi = 0; mi < 4; ++mi) av0[mi] = LDSF(0,     wr4 + mi); \
    _Pragma("unroll") for (int mi = 0; mi < 4; ++mi) av1[mi] = LDSF(4096,  wr4 + mi); \
    _Pragma("unroll") for (int ni = 0; ni < 4; ++ni) bv0[ni] = LDSF(8192,  wc4 + ni); \
    _Pragma("unroll") for (int ni = 0; ni < 4; ++ni) bv1[ni] = LDSF(12288, wc4 + ni); \
    asm volatile("s_waitcnt lgkmcnt(0)" ::: "memory"); \
    SBAR0(); \
    __builtin_amdgcn_s_barrier();  /* B: all waves consumed cur buf */ \
    SBAR0(); /* pin: MFMAs + next stage stay AFTER barrier B */ \
    __builtin_amdgcn_s_setprio(1); \
    _Pragma("unroll") for (int mi = 0; mi < 4; ++mi) \
    _Pragma("unroll") for (int ni = 0; ni < 4; ++ni) \
        accH[mi][ni] = __builtin_amdgcn_mfma_f32_16x16x32_f16(av0[mi], bv0[ni], accH[mi][ni], 0, 0, 0); \
    _Pragma("unroll") for (int mi = 0; mi < 4; ++mi) \
    _Pragma("unroll") for (int ni = 0; ni < 4; ++ni) \
        accL[mi][ni] = __builtin_amdgcn_mfma_f32_16x16x32_f16(av0[mi], bv1[ni], accL[mi][ni], 0, 0, 0); \
    _Pragma("unroll") for (int mi = 0; mi < 4; ++mi) \
    _Pragma("unroll") for (int ni = 0; ni < 4; ++ni) \
        accL[mi][ni] = __builtin_amdgcn_mfma_f32_16x16x32_f16(av1[mi], bv0[ni], accL[mi][ni], 0, 0, 0); \
    __builtin_amdgcn_s_setprio(0); \
} while (0)

    STAGE8(0);                       // tile 0 -> buf0 (8 loads in flight)
    for (int step = 0; step < 31; ++step) {
        const int cur = (step & 1) * 16384;
        STAGE8((step + 1) & 1);      // tile t+1 (8 newest loads)
        SBAR0();                     // pin: stage issued before the wait
        asm volatile("s_waitcnt vmcnt(8)" ::: "memory");  // tile t landed
        SBAR0();
        __builtin_amdgcn_s_barrier();                     // A: cur buf ready
        COMPUTE();
    }
    {   // peeled step 31: nothing left to stage; drain tile 31 fully
        const int cur = 16384;
        SBAR0();
        asm volatile("s_waitcnt vmcnt(0)" ::: "memory");
        SBAR0();
        __builtin_amdgcn_s_barrier();
        COMPUTE();
    }

    // epilogue: C/D layout col=lane&15, row=(lane>>4)*4+r (verified r2/r4/r5)
#pragma unroll
    for (int ni = 0; ni < 4; ++ni) {
        const int col = bn + wc * 64 + ni * 16 + lr;
        const float bb = bias[col];
#pragma unroll
        for (int mi = 0; mi < 4; ++mi) {
            const long rbase = bm + wr * 64 + mi * 16 + lk * 4;
#pragma unroll
            for (int r = 0; r < 4; ++r) {
                const long row = rbase + r;
                if (row < MDIM) {
                    const float v = accH[mi][ni][r] + SPLIT_INV * accL[mi][ni][r];
                    const float hv = fmaxf(v + bb, 0.f);
                    if (MODE == 1 || MODE == 2) outF[row * DDIM + col] = hv;
                    if (MODE == 0 || MODE == 2) {
                        const _Float16 h0 = (_Float16)hv;
                        H0[row * DDIM + col] = h0;
                        H1[row * DDIM + col] = (_Float16)((hv - (float)h0) * SPLIT_SCALE);
                    }
                }
            }
        }
    }
#undef COMPUTE
#undef LDSF
#undef STAGE8
}

// ---------------------------------------------------------------------------
// cls/at heads via split-f16 MFMA (3-panel rel err ~2^-20 << mask budget).
// A = x splits [24000][1024]; B = combined W splits [64][1024].
// Tile 64 rows x 48 cols; 375 blocks; r8 skeleton.
// ---------------------------------------------------------------------------
__global__ __launch_bounds__(256, 2)
void cls_mfma_f16(const _Float16* __restrict__ A0, const _Float16* __restrict__ A1,
                  const _Float16* __restrict__ B0, const _Float16* __restrict__ B1,
                  const float* __restrict__ bc, const float* __restrict__ ba,
                  float* __restrict__ clsx, float* __restrict__ atout) {
    __shared__ _Float16 sm[16384];   // 2 buf x (A0 2048|A1 2048|B0 2048|B1 2048)
    const int t = threadIdx.x;
    const int lane = t & 63;
    const int wave = t >> 6;         // 0..3
    const int lr = lane & 15, lk = lane >> 4;
    const long bm = (long)blockIdx.x * 64;

    const int r_in = lane >> 2;          // 0..15
    const int c8 = (lane & 3) << 3;      // 0,8,16,24 f16
    const long raA = bm + wave * 16 + r_in;          // < 24000 exactly
    const long raB = (long)(wave * 16 + r_in);       // 0..63
    const _Float16* pA0 = A0 + (raA << 10) + c8;
    const _Float16* pA1 = A1 + (raA << 10) + c8;
    const _Float16* pB0 = B0 + (raB << 10) + c8;
    const _Float16* pB1 = B1 + (raB << 10) + c8;
    const int sb = wave * 512 + lane * 8;

#define CSTAGE(par) do { \
    _Float16* _d = sm + (par) * 8192; \
    GLOAD16(pA0, _d + sb); \
    GLOAD16(pA1, _d + 2048 + sb); \
    GLOAD16(pB0, _d + 4096 + sb); \
    GLOAD16(pB1, _d + 6144 + sb); \
    pA0 += 32; pA1 += 32; pB0 += 32; pB1 += 32; \
} while (0)

#define CLDS(tileoff, rb) (*(const f16x8*)&sm[cur + (tileoff) + (rb) * 512 + lr * 32 + lk * 8])

    f32x4 accH[3], accL[3];
#pragma unroll
    for (int ni = 0; ni < 3; ++ni) {
        accH[ni] = (f32x4){0.f, 0.f, 0.f, 0.f};
        accL[ni] = (f32x4){0.f, 0.f, 0.f, 0.f};
    }
    f16x8 av0, av1, bv0[3], bv1[3];

#define CCOMPUTE() do { \
    SBAR0(); \
    av0 = CLDS(0, wave); \
    av1 = CLDS(2048, wave); \
    _Pragma("unroll") for (int ni = 0; ni < 3; ++ni) bv0[ni] = CLDS(4096, ni); \
    _Pragma("unroll") for (int ni = 0; ni < 3; ++ni) bv1[ni] = CLDS(6144, ni); \
    asm volatile("s_waitcnt lgkmcnt(0)" ::: "memory"); \
    SBAR0(); \
    __builtin_amdgcn_s_barrier(); \
    SBAR0(); \
    _Pragma("unroll") for (int ni = 0; ni < 3; ++ni) \
        accH[ni] = __builtin_amdgcn_mfma_f32_16x16x32_f16(av0, bv0[ni], accH[ni], 0, 0, 0); \
    _Pragma("unroll") for (int ni = 0; ni < 3; ++ni) \
        accL[ni] = __builtin_amdgcn_mfma_f32_16x16x32_f16(av0, bv1[ni], accL[ni], 0, 0, 0); \
    _Pragma("unroll") for (int ni = 0; ni < 3; ++ni) \
        accL[ni] = __builtin_amdgcn_mfma_f32_16x16x32_f16(av1, bv0[ni], accL[ni], 0, 0, 0); \
} while (0)

    CSTAGE(0);
    for (int step = 0; step < 31; ++step) {
        const int cur = (step & 1) * 8192;
        CSTAGE((step + 1) & 1);
        SBAR0();
        asm volatile("s_waitcnt vmcnt(4)" ::: "memory");
        SBAR0();
        __builtin_amdgcn_s_barrier();
        CCOMPUTE();
    }
    {
        const int cur = 8192;
        SBAR0();
        asm volatile("s_waitcnt vmcnt(0)" ::: "memory");
        SBAR0();
        __builtin_amdgcn_s_barrier();
        CCOMPUTE();
    }

#pragma unroll
    for (int ni = 0; ni < 3; ++ni) {
        const int col = ni * 16 + lr;                 // 0..47
        const float bvv = (col < 20) ? bc[col] : ((col < 40) ? ba[col - 20] : 0.f);
#pragma unroll
        for (int r = 0; r < 4; ++r) {
            const long row = bm + wave * 16 + lk * 4 + r;
            const float v = accH[ni][r] + SPLIT_INV * accL[ni][r] + bvv;
            if (col < 20)      clsx[row * CDIM + col] = v;
            else if (col < 40) atout[row * CDIM + col - 20] = v;
        }
    }
#undef CCOMPUTE
#undef CLDS
#undef CSTAGE
}

// ---------------------------------------------------------------------------
// Exact rank-KSEL selection per (stream,n,c): 4-pass radix-select on
// sortable-uint keys; per-pass digit scan parallelized (Hillis-Steele in
// LDS, unique-winner commit) instead of the r16 serial tid0 loop.
// ---------------------------------------------------------------------------
__global__ __launch_bounds__(256)
void select_kth(const float* __restrict__ clsx_r, const float* __restrict__ clsx_f,
                float* __restrict__ kth) {
    __shared__ uint32_t su[TDIM];
    __shared__ uint32_t hist[256];
    __shared__ uint32_t sc[256];
    __shared__ uint32_t s_prefix, s_rank, s_mask;
    const int b = blockIdx.x;
    const int z = b / 640;
    const int rem = b - z * 640;
    const int n = rem / CDIM;
    const int c = rem - n * CDIM;
    const float* src = (z == 0) ? clsx_r : clsx_f;
    const int tid = threadIdx.x;

    for (int i = tid; i < TDIM; i += 256) {
        const uint32_t bits = __float_as_uint(src[((long)n * TDIM + i) * CDIM + c]);
        su[i] = (bits & 0x80000000u) ? ~bits : (bits | 0x80000000u);
    }
    if (tid == 0) { s_prefix = 0; s_rank = KSEL; s_mask = 0; }
    __syncthreads();

#pragma unroll
    for (int pass = 0; pass < 4; ++pass) {
        const int shift = 24 - pass * 8;
        hist[tid] = 0;
        __syncthreads();
        const uint32_t pfx = s_prefix, msk = s_mask, rk = s_rank;
        for (int i = tid; i < TDIM; i += 256) {
            const uint32_t u = su[i];
            if ((u & msk) == pfx) atomicAdd(&hist[(u >> shift) & 255u], 1u);
        }
        __syncthreads();
        // inclusive scan over the 256 digit counts (Hillis-Steele)
        sc[tid] = hist[tid];
        __syncthreads();
#pragma unroll
        for (int off = 1; off < 256; off <<= 1) {
            const uint32_t add = (tid >= off) ? sc[tid - off] : 0u;
            __syncthreads();
            sc[tid] += add;
            __syncthreads();
        }
        const uint32_t incl = sc[tid];
        const uint32_t excl = incl - hist[tid];
        if (excl < rk && incl >= rk) {          // unique winning digit
            s_prefix = pfx | ((uint32_t)tid << shift);
            s_rank   = rk - excl;
            s_mask   = msk | (0xffu << shift);
        }
        __syncthreads();
    }
    if (tid == 0) {
        const uint32_t u = s_prefix;
        kth[b] = (u & 0x80000000u) ? __uint_as_float(u ^ 0x80000000u)
                                   : __uint_as_float(~u);
    }
}

__global__ __launch_bounds__(256)
void final_mask(float* __restrict__ out, const float* __restrict__ kth,
                const float* __restrict__ mul_r, const float* __restrict__ mul_f) {
    const int idx = blockIdx.x * 256 + threadIdx.x;
    if (idx >= NBATCH * TDIM * CDIM) return;
    const int m = idx / CDIM;
    const int c = idx - m * CDIM;
    const int n = m / TDIM;
    const float xr  = out[OFF_CLSX_R + idx];
    const float xf  = out[OFF_CLSX_F + idx];
    const float atr = out[OFF_CLSRA + idx];
    const float atf = out[OFF_CLSFA + idx];
    const float kr = kth[n * CDIM + c];
    const float kf = kth[640 + n * CDIM + c];
    out[OFF_CLSRA + idx] = (xr > kr) ? MASKV : atr;
    out[OFF_CLSFA + idx] = (xf > kf) ? MASKV : atf;
    out[OFF_TCAM + idx]  = (xr + OMEGAF * atr) * mul_r[c] + (xf + OMEGAF * atf) * mul_f[c];
}

extern "C" void kernel_launch(void* const* d_in, const int* in_sizes, int n_in,
                              void* d_out, int out_size, void* d_ws, size_t ws_size,
                              hipStream_t stream) {
    const float* inp    = (const float*)d_in[0];
    const float* Wfc_r  = (const float*)d_in[1];
    const float* bfc_r  = (const float*)d_in[2];
    const float* Wfc1_r = (const float*)d_in[3];
    const float* bfc1_r = (const float*)d_in[4];
    const float* Wfc_f  = (const float*)d_in[5];
    const float* bfc_f  = (const float*)d_in[6];
    const float* Wfc1_f = (const float*)d_in[7];
    const float* bfc1_f = (const float*)d_in[8];
    const float* Wcls_r = (const float*)d_in[9];
    const float* bcls_r = (const float*)d_in[10];
    const float* Wcls_f = (const float*)d_in[11];
    const float* bcls_f = (const float*)d_in[12];
    const float* Wra    = (const float*)d_in[13];
    const float* bra    = (const float*)d_in[14];
    const float* Wfa    = (const float*)d_in[15];
    const float* bfa    = (const float*)d_in[16];
    const float* mul_r  = (const float*)d_in[17];
    const float* mul_f  = (const float*)d_in[18];

    float* out = (float*)d_out;
    _Float16* wsA0 = (_Float16*)d_ws;            // 24000x1024 each
    _Float16* wsA1 = wsA0 + 24576000L;
    _Float16* wsH0 = wsA1 + 24576000L;
    _Float16* wsH1 = wsH0 + 24576000L;
    _Float16* wsW  = wsH1 + 24576000L;           // 8 x 1024x1024 f16
    _Float16* wsWc = wsW + 8L * 1048576L;        // 4 x 64x1024 f16 (cls W splits)
    float* kth = (float*)(wsWc + 4L * 65536L);   // 1280 f32

    dim3 blk(256);
    dim3 gg(1504);

    // weight order: [0]=Wfc_r, [1]=Wfc1_r, [2]=Wfc_f, [3]=Wfc1_f
    split_w4<<<dim3(2048), blk, 0, stream>>>(Wfc_r, Wfc1_r, Wfc_f, Wfc1_f, wsW);
    split_clsW2<<<dim3(512), blk, 0, stream>>>(Wcls_r, Wra, Wcls_f, Wfa, wsWc);

    // ---- RGB stream ----
    split_f16<<<dim3(2048), blk, 0, stream>>>(inp, 2 * DDIM, MDIM, wsA0, wsA1);
    gemm_fused_f16<0><<<gg, blk, 0, stream>>>(wsA0, wsA1, wsW + 0L * 1048576, wsW + 1L * 1048576,
                                              bfc_r, nullptr, wsH0, wsH1);
    gemm_fused_f16<2><<<gg, blk, 0, stream>>>(wsH0, wsH1, wsW + 2L * 1048576, wsW + 3L * 1048576,
                                              bfc1_r, out + OFF_XR, wsA0, wsA1);
    cls_mfma_f16<<<dim3(375), blk, 0, stream>>>(wsA0, wsA1, wsWc + 0L * 65536, wsWc + 1L * 65536,
                                                bcls_r, bra, out + OFF_CLSX_R, out + OFF_CLSRA);

    // ---- Flow stream ----
    split_f16<<<dim3(2048), blk, 0, stream>>>(inp + DDIM, 2 * DDIM, MDIM, wsA0, wsA1);
    gemm_fused_f16<0><<<gg, blk, 0, stream>>>(wsA0, wsA1, wsW + 4L * 1048576, wsW + 5L * 1048576,
                                              bfc_f, nullptr, wsH0, wsH1);
    gemm_fused_f16<2><<<gg, blk, 0, stream>>>(wsH0, wsH1, wsW + 6L * 1048576, wsW + 7L * 1048576,
                                              bfc1_f, out + OFF_XF, wsA0, wsA1);
    cls_mfma_f16<<<dim3(375), blk, 0, stream>>>(wsA0, wsA1, wsWc + 2L * 65536, wsWc + 3L * 65536,
                                                bcls_f, bfa, out + OFF_CLSX_F, out + OFF_CLSFA);

    select_kth<<<dim3(1280), blk, 0, stream>>>(out + OFF_CLSX_R, out + OFF_CLSX_F, kth);
    final_mask<<<dim3((NBATCH * TDIM * CDIM + 255) / 256), blk, 0, stream>>>(out, kth, mul_r, mul_f);
}

// Round 18
// 874.048 us; speedup vs baseline: 1.9169x; 1.0314x over previous
//
#include <hip/hip_runtime.h>
#include <cstdint>

typedef _Float16 f16x8 __attribute__((ext_vector_type(8)));
typedef float f32x4 __attribute__((ext_vector_type(4)));

#define MDIM 24000   // N*T rows
#define DDIM 1024
#define CDIM 20
#define TDIM 750
#define NBATCH 32
#define KSEL 657
#define MASKV -100.0f
#define OMEGAF 0.6f
#define SPLIT_SCALE 2048.0f
#define SPLIT_INV   4.8828125e-4f   // 2^-11 exact

// d_out element offsets (x_r, cls_x_r, cls_x_ra, x_f, cls_x_f, cls_x_fa, tcam)
#define OFF_XR     0L
#define OFF_CLSX_R 24576000L
#define OFF_CLSRA  25056000L
#define OFF_XF     25536000L
#define OFF_CLSX_F 50112000L
#define OFF_CLSFA  50592000L
#define OFF_TCAM   51072000L

#define GLOAD16(g, l) __builtin_amdgcn_global_load_lds( \
    (const __attribute__((address_space(1))) void*)(g), \
    (__attribute__((address_space(3))) void*)(l), 16, 0, 0)

#define SBAR0() __builtin_amdgcn_sched_barrier(0)

// ---------------------------------------------------------------------------
// weight-split helpers (input splits are now fused into layer-1)
// ---------------------------------------------------------------------------
// All four 1024x1024 FC-weight splits in ONE launch.
__global__ __launch_bounds__(256)
void split_w4(const float* __restrict__ W0, const float* __restrict__ W1,
              const float* __restrict__ W2, const float* __restrict__ W3,
              _Float16* __restrict__ Dbase) {
    const int wi = blockIdx.x >> 9;                 // 0..3
    const int bid = blockIdx.x & 511;
    const float* __restrict__ src = (wi == 0) ? W0 : (wi == 1) ? W1 : (wi == 2) ? W2 : W3;
    _Float16* __restrict__ D0 = Dbase + (long)(2 * wi) * 1048576L;
    _Float16* __restrict__ D1 = D0 + 1048576L;
    for (long v = (long)bid * 256 + threadIdx.x; v < 131072L; v += 512L * 256) {
        const long row = v >> 7;
        const int c8 = (int)(v & 127) << 3;
        const float4 x0 = *reinterpret_cast<const float4*>(&src[row * 1024 + c8]);
        const float4 x1 = *reinterpret_cast<const float4*>(&src[row * 1024 + c8 + 4]);
        float xs[8] = {x0.x, x0.y, x0.z, x0.w, x1.x, x1.y, x1.z, x1.w};
        f16x8 h0, h1;
#pragma unroll
        for (int j = 0; j < 8; ++j) {
            const _Float16 a = (_Float16)xs[j];
            h0[j] = a;
            h1[j] = (_Float16)((xs[j] - (float)a) * SPLIT_SCALE);
        }
        *reinterpret_cast<f16x8*>(&D0[v << 3]) = h0;
        *reinterpret_cast<f16x8*>(&D1[v << 3]) = h1;
    }
}

// Both streams' cls-W combines in ONE launch; pad rows zeroed EVERY call.
__global__ __launch_bounds__(256)
void split_clsW2(const float* __restrict__ Wc_r, const float* __restrict__ Wa_r,
                 const float* __restrict__ Wc_f, const float* __restrict__ Wa_f,
                 _Float16* __restrict__ Dbase) {
    const int z = blockIdx.x >> 8;                  // 0..1
    const int idx = (blockIdx.x & 255) * 256 + threadIdx.x;   // 0..65535
    const float* __restrict__ Wc = z ? Wc_f : Wc_r;
    const float* __restrict__ Wa = z ? Wa_f : Wa_r;
    _Float16* __restrict__ D0 = Dbase + (long)z * 131072L;
    _Float16* __restrict__ D1 = D0 + 65536L;
    const int r = idx >> 10;
    const int c = idx & 1023;
    float v = 0.f;
    if (r < 20)      v = Wc[r * 1024 + c];
    else if (r < 40) v = Wa[(r - 20) * 1024 + c];
    const _Float16 h0 = (_Float16)v;
    D0[idx] = h0;
    D1[idx] = (_Float16)((v - (float)h0) * SPLIT_SCALE);
}

// ---------------------------------------------------------------------------
// Layer-1 GEMM: A staged as RAW FP32 from the strided input (stride 2048),
// split to (h0, h1*2^11) IN-REGISTER after the LDS read — the standalone
// input-split kernels are gone.  r8 skeleton preserved EXACTLY:
//   per step: STAGE(t+1) = 4 A-subtile gload_lds (1KB each, fp32) + 4 B
//   loads = 8/thread -> vmcnt(8) -> barrier A -> LDS reads -> lgkmcnt(0)
//   -> barrier B -> 48 MFMA.  LDS 64 KiB (A-f32 16K + B0 8K + B1 8K per buf).
// FP32 rows are 128 B => 16B-chunk XOR swizzle chunk^=(row&7), applied on
// BOTH sides (rule 21): pre-swizzled per-lane GLOBAL source (linear LDS
// dest) + swizzled read.  Conversion math bit-identical to split_f16 (RNE).
// ---------------------------------------------------------------------------
__global__ __launch_bounds__(256, 2)
void gemm_l1_f32a(const float* __restrict__ Ax,          // + stream offset
                  const _Float16* __restrict__ B0, const _Float16* __restrict__ B1,
                  const float* __restrict__ bias,
                  _Float16* __restrict__ H0, _Float16* __restrict__ H1) {
    __shared__ _Float16 sm[32768];   // 64 KiB
    uint8_t* const smb = (uint8_t*)sm;
    const int t = threadIdx.x;
    const int lane = t & 63;
    const int wave = t >> 6;
    const int wr = wave >> 1, wc = wave & 1;
    const int lr = lane & 15, lk = lane >> 4;
    const int wr4 = wr * 4, wc4 = wc * 4;

    const int bid = blockIdx.x;
    const int wg = (bid & 7) * 188 + (bid >> 3);
    const long bm = (long)(wg >> 3) * 128;
    const int bn = (wg & 7) * 128;

    // ---- A stage: subtile s = wave*4+q (8 rows x 128B); lane l writes LDS
    // chunk p=l&7 of inner row i=l>>3; global source chunk = p ^ i.
    const int irow = lane >> 3;                  // 0..7
    const int schunk = (lane & 7) ^ irow;        // swizzled source chunk
    const float* pA[4];
#pragma unroll
    for (int q = 0; q < 4; ++q) {
        long ra = bm + (wave * 4 + q) * 8 + irow;
        if (ra > MDIM - 1) ra = MDIM - 1;
        pA[q] = Ax + ra * 2048L + schunk * 4;
    }
    // ---- B stage (identical to r8's B half; f16 16x32 subtiles)
    const int r_in = lane >> 2;
    const int c8 = (lane & 3) << 3;
    const long rb0 = (long)(bn + (wave * 2 + 0) * 16 + r_in);
    const long rb1 = (long)(bn + (wave * 2 + 1) * 16 + r_in);
    const _Float16* pB0a = B0 + (rb0 << 10) + c8;
    const _Float16* pB0b = B0 + (rb1 << 10) + c8;
    const _Float16* pB1a = B1 + (rb0 << 10) + c8;
    const _Float16* pB1b = B1 + (rb1 << 10) + c8;
    const int sb0 = (wave * 2 + 0) * 512 + lane * 8;
    const int sb1 = (wave * 2 + 1) * 512 + lane * 8;

#define STAGE8(par) do { \
    _Pragma("unroll") for (int q = 0; q < 4; ++q) { \
        GLOAD16(pA[q], smb + (par) * 32768 + (wave * 4 + q) * 1024 + lane * 16); \
        pA[q] += 32; } \
    _Float16* _d = sm + (par) * 16384; \
    GLOAD16(pB0a, _d + 8192 + sb0);  GLOAD16(pB0b, _d + 8192 + sb1); \
    GLOAD16(pB1a, _d + 12288 + sb0); GLOAD16(pB1b, _d + 12288 + sb1); \
    pB0a += 32; pB0b += 32; pB1a += 32; pB1b += 32; \
} while (0)

#define LDSB(tileoff, rb) (*(const f16x8*)&sm[cur * 16384 + (tileoff) + (rb) * 512 + lr * 32 + lk * 8])

    f32x4 accH[4][4], accL[4][4];
#pragma unroll
    for (int mi = 0; mi < 4; ++mi)
#pragma unroll
        for (int ni = 0; ni < 4; ++ni) {
            accH[mi][ni] = (f32x4){0.f, 0.f, 0.f, 0.f};
            accL[mi][ni] = (f32x4){0.f, 0.f, 0.f, 0.f};
        }

    f16x8 av0[4], av1[4], bv0[4], bv1[4];

#define COMPUTE() do { \
    SBAR0(); /* pin: reads stay AFTER barrier A */ \
    f32x4 xlo[4], xhi[4]; \
    _Pragma("unroll") for (int mi = 0; mi < 4; ++mi) { \
        const int r = wr4 * 16 + mi * 16 + lr; \
        const int ab = cur * 32768 + (r >> 3) * 1024 + (r & 7) * 128; \
        xlo[mi] = *(const f32x4*)(smb + ab + ((((lk * 2 + 0) ^ (r & 7))) << 4)); \
        xhi[mi] = *(const f32x4*)(smb + ab + ((((lk * 2 + 1) ^ (r & 7))) << 4)); \
    } \
    _Pragma("unroll") for (int ni = 0; ni < 4; ++ni) bv0[ni] = LDSB(8192,  wc4 + ni); \
    _Pragma("unroll") for (int ni = 0; ni < 4; ++ni) bv1[ni] = LDSB(12288, wc4 + ni); \
    asm volatile("s_waitcnt lgkmcnt(0)" ::: "memory"); \
    SBAR0(); \
    __builtin_amdgcn_s_barrier();  /* B: all waves consumed cur buf */ \
    SBAR0(); /* pin: MFMAs + next stage stay AFTER barrier B */ \
    _Pragma("unroll") for (int mi = 0; mi < 4; ++mi) { \
        f16x8 h0v, h1v; \
        _Pragma("unroll") for (int j = 0; j < 4; ++j) { \
            const _Float16 a = (_Float16)xlo[mi][j]; \
            h0v[j] = a; h1v[j] = (_Float16)((xlo[mi][j] - (float)a) * SPLIT_SCALE); \
        } \
        _Pragma("unroll") for (int j = 0; j < 4; ++j) { \
            const _Float16 a = (_Float16)xhi[mi][j]; \
            h0v[4 + j] = a; h1v[4 + j] = (_Float16)((xhi[mi][j] - (float)a) * SPLIT_SCALE); \
        } \
        av0[mi] = h0v; av1[mi] = h1v; \
    } \
    __builtin_amdgcn_s_setprio(1); \
    _Pragma("unroll") for (int mi = 0; mi < 4; ++mi) \
    _Pragma("unroll") for (int ni = 0; ni < 4; ++ni) \
        accH[mi][ni] = __builtin_amdgcn_mfma_f32_16x16x32_f16(av0[mi], bv0[ni], accH[mi][ni], 0, 0, 0); \
    _Pragma("unroll") for (int mi = 0; mi < 4; ++mi) \
    _Pragma("unroll") for (int ni = 0; ni < 4; ++ni) \
        accL[mi][ni] = __builtin_amdgcn_mfma_f32_16x16x32_f16(av0[mi], bv1[ni], accL[mi][ni], 0, 0, 0); \
    _Pragma("unroll") for (int mi = 0; mi < 4; ++mi) \
    _Pragma("unroll") for (int ni = 0; ni < 4; ++ni) \
        accL[mi][ni] = __builtin_amdgcn_mfma_f32_16x16x32_f16(av1[mi], bv0[ni], accL[mi][ni], 0, 0, 0); \
    __builtin_amdgcn_s_setprio(0); \
} while (0)

    STAGE8(0);                       // tile 0 -> buf0 (8 loads in flight)
    for (int step = 0; step < 31; ++step) {
        const int cur = step & 1;
        STAGE8((step + 1) & 1);      // tile t+1 (8 newest loads)
        SBAR0();                     // pin: stage issued before the wait
        asm volatile("s_waitcnt vmcnt(8)" ::: "memory");  // tile t landed
        SBAR0();
        __builtin_amdgcn_s_barrier();                     // A: cur buf ready
        COMPUTE();
    }
    {   // peeled step 31: nothing left to stage; drain tile 31 fully
        const int cur = 1;
        SBAR0();
        asm volatile("s_waitcnt vmcnt(0)" ::: "memory");
        SBAR0();
        __builtin_amdgcn_s_barrier();
        COMPUTE();
    }

    // epilogue: write H splits (MODE0); C/D layout col=lane&15, row=(lane>>4)*4+r
#pragma unroll
    for (int ni = 0; ni < 4; ++ni) {
        const int col = bn + wc * 64 + ni * 16 + lr;
        const float bb = bias[col];
#pragma unroll
        for (int mi = 0; mi < 4; ++mi) {
            const long rbase = bm + wr * 64 + mi * 16 + lk * 4;
#pragma unroll
            for (int r = 0; r < 4; ++r) {
                const long row = rbase + r;
                if (row < MDIM) {
                    const float v = accH[mi][ni][r] + SPLIT_INV * accL[mi][ni][r];
                    const float hv = fmaxf(v + bb, 0.f);
                    const _Float16 h0 = (_Float16)hv;
                    H0[row * DDIM + col] = h0;
                    H1[row * DDIM + col] = (_Float16)((hv - (float)h0) * SPLIT_SCALE);
                }
            }
        }
    }
#undef COMPUTE
#undef LDSB
#undef STAGE8
}

// ---------------------------------------------------------------------------
// Layer-2 GEMM (r8 validated skeleton, f16-split A via MODE2 outputs).
// ---------------------------------------------------------------------------
template<int MODE>
__global__ __launch_bounds__(256, 2)
void gemm_fused_f16(const _Float16* __restrict__ A0, const _Float16* __restrict__ A1,
                    const _Float16* __restrict__ B0, const _Float16* __restrict__ B1,
                    const float* __restrict__ bias,
                    float* __restrict__ outF,
                    _Float16* __restrict__ H0, _Float16* __restrict__ H1) {
    __shared__ _Float16 sm[32768];   // 2 x 16384 f16 (A0|A1|B0|B1 tiles)
    const int t = threadIdx.x;
    const int lane = t & 63;
    const int wave = t >> 6;
    const int wr = wave >> 1, wc = wave & 1;
    const int lr = lane & 15, lk = lane >> 4;
    const int wr4 = wr * 4, wc4 = wc * 4;

    const int bid = blockIdx.x;
    const int wg = (bid & 7) * 188 + (bid >> 3);
    const long bm = (long)(wg >> 3) * 128;
    const int bn = (wg & 7) * 128;

    const int r_in = lane >> 2;
    const int c8 = (lane & 3) << 3;
    long ra0 = bm + (wave * 2 + 0) * 16 + r_in; if (ra0 > MDIM - 1) ra0 = MDIM - 1;
    long ra1 = bm + (wave * 2 + 1) * 16 + r_in; if (ra1 > MDIM - 1) ra1 = MDIM - 1;
    const long rb0 = (long)(bn + (wave * 2 + 0) * 16 + r_in);
    const long rb1 = (long)(bn + (wave * 2 + 1) * 16 + r_in);
    const _Float16* pA0a = A0 + (ra0 << 10) + c8;
    const _Float16* pA0b = A0 + (ra1 << 10) + c8;
    const _Float16* pA1a = A1 + (ra0 << 10) + c8;
    const _Float16* pA1b = A1 + (ra1 << 10) + c8;
    const _Float16* pB0a = B0 + (rb0 << 10) + c8;
    const _Float16* pB0b = B0 + (rb1 << 10) + c8;
    const _Float16* pB1a = B1 + (rb0 << 10) + c8;
    const _Float16* pB1b = B1 + (rb1 << 10) + c8;
    const int sb0 = (wave * 2 + 0) * 512 + lane * 8;
    const int sb1 = (wave * 2 + 1) * 512 + lane * 8;

#define STAGE8(par) do { \
    _Float16* _d = sm + (par) * 16384; \
    GLOAD16(pA0a, _d + sb0);         GLOAD16(pA0b, _d + sb1); \
    GLOAD16(pA1a, _d + 4096 + sb0);  GLOAD16(pA1b, _d + 4096 + sb1); \
    GLOAD16(pB0a, _d + 8192 + sb0);  GLOAD16(pB0b, _d + 8192 + sb1); \
    GLOAD16(pB1a, _d + 12288 + sb0); GLOAD16(pB1b, _d + 12288 + sb1); \
    pA0a += 32; pA0b += 32; pA1a += 32; pA1b += 32; \
    pB0a += 32; pB0b += 32; pB1a += 32; pB1b += 32; \
} while (0)

#define LDSF(tileoff, rb) (*(const f16x8*)&sm[cur + (tileoff) + (rb) * 512 + lr * 32 + lk * 8])

    f32x4 accH[4][4], accL[4][4];
#pragma unroll
    for (int mi = 0; mi < 4; ++mi)
#pragma unroll
        for (int ni = 0; ni < 4; ++ni) {
            accH[mi][ni] = (f32x4){0.f, 0.f, 0.f, 0.f};
            accL[mi][ni] = (f32x4){0.f, 0.f, 0.f, 0.f};
        }

    f16x8 av0[4], av1[4], bv0[4], bv1[4];

#define COMPUTE() do { \
    SBAR0(); /* pin: reads stay AFTER barrier A */ \
    _Pragma("unroll") for (int mi = 0; mi < 4; ++mi) av0[mi] = LDSF(0,     wr4 + mi); \
    _Pragma("unroll") for (int mi = 0; mi < 4; ++mi) av1[mi] = LDSF(4096,  wr4 + mi); \
    _Pragma("unroll") for (int ni = 0; ni < 4; ++ni) bv0[ni] = LDSF(8192,  wc4 + ni); \
    _Pragma("unroll") for (int ni = 0; ni < 4; ++ni) bv1[ni] = LDSF(12288, wc4 + ni); \
    asm volatile("s_waitcnt lgkmcnt(0)" ::: "memory"); \
    SBAR0(); \
    __builtin_amdgcn_s_barrier();  /* B: all waves consumed cur buf */ \
    SBAR0(); /* pin: MFMAs + next stage stay AFTER barrier B */ \
    __builtin_amdgcn_s_setprio(1); \
    _Pragma("unroll") for (int mi = 0; mi < 4; ++mi) \
    _Pragma("unroll") for (int ni = 0; ni < 4; ++ni) \
        accH[mi][ni] = __builtin_amdgcn_mfma_f32_16x16x32_f16(av0[mi], bv0[ni], accH[mi][ni], 0, 0, 0); \
    _Pragma("unroll") for (int mi = 0; mi < 4; ++mi) \
    _Pragma("unroll") for (int ni = 0; ni < 4; ++ni) \
        accL[mi][ni] = __builtin_amdgcn_mfma_f32_16x16x32_f16(av0[mi], bv1[ni], accL[mi][ni], 0, 0, 0); \
    _Pragma("unroll") for (int mi = 0; mi < 4; ++mi) \
    _Pragma("unroll") for (int ni = 0; ni < 4; ++ni) \
        accL[mi][ni] = __builtin_amdgcn_mfma_f32_16x16x32_f16(av1[mi], bv0[ni], accL[mi][ni], 0, 0, 0); \
    __builtin_amdgcn_s_setprio(0); \
} while (0)

    STAGE8(0);
    for (int step = 0; step < 31; ++step) {
        const int cur = (step & 1) * 16384;
        STAGE8((step + 1) & 1);
        SBAR0();
        asm volatile("s_waitcnt vmcnt(8)" ::: "memory");
        SBAR0();
        __builtin_amdgcn_s_barrier();
        COMPUTE();
    }
    {
        const int cur = 16384;
        SBAR0();
        asm volatile("s_waitcnt vmcnt(0)" ::: "memory");
        SBAR0();
        __builtin_amdgcn_s_barrier();
        COMPUTE();
    }

#pragma unroll
    for (int ni = 0; ni < 4; ++ni) {
        const int col = bn + wc * 64 + ni * 16 + lr;
        const float bb = bias[col];
#pragma unroll
        for (int mi = 0; mi < 4; ++mi) {
            const long rbase = bm + wr * 64 + mi * 16 + lk * 4;
#pragma unroll
            for (int r = 0; r < 4; ++r) {
                const long row = rbase + r;
                if (row < MDIM) {
                    const float v = accH[mi][ni][r] + SPLIT_INV * accL[mi][ni][r];
                    const float hv = fmaxf(v + bb, 0.f);
                    if (MODE == 1 || MODE == 2) outF[row * DDIM + col] = hv;
                    if (MODE == 0 || MODE == 2) {
                        const _Float16 h0 = (_Float16)hv;
                        H0[row * DDIM + col] = h0;
                        H1[row * DDIM + col] = (_Float16)((hv - (float)h0) * SPLIT_SCALE);
                    }
                }
            }
        }
    }
#undef COMPUTE
#undef LDSF
#undef STAGE8
}

// ---------------------------------------------------------------------------
// cls/at heads via split-f16 MFMA (3-panel rel err ~2^-20 << mask budget).
// ---------------------------------------------------------------------------
__global__ __launch_bounds__(256, 2)
void cls_mfma_f16(const _Float16* __restrict__ A0, const _Float16* __restrict__ A1,
                  const _Float16* __restrict__ B0, const _Float16* __restrict__ B1,
                  const float* __restrict__ bc, const float* __restrict__ ba,
                  float* __restrict__ clsx, float* __restrict__ atout) {
    __shared__ _Float16 sm[16384];
    const int t = threadIdx.x;
    const int lane = t & 63;
    const int wave = t >> 6;
    const int lr = lane & 15, lk = lane >> 4;
    const long bm = (long)blockIdx.x * 64;

    const int r_in = lane >> 2;
    const int c8 = (lane & 3) << 3;
    const long raA = bm + wave * 16 + r_in;
    const long raB = (long)(wave * 16 + r_in);
    const _Float16* pA0 = A0 + (raA << 10) + c8;
    const _Float16* pA1 = A1 + (raA << 10) + c8;
    const _Float16* pB0 = B0 + (raB << 10) + c8;
    const _Float16* pB1 = B1 + (raB << 10) + c8;
    const int sb = wave * 512 + lane * 8;

#define CSTAGE(par) do { \
    _Float16* _d = sm + (par) * 8192; \
    GLOAD16(pA0, _d + sb); \
    GLOAD16(pA1, _d + 2048 + sb); \
    GLOAD16(pB0, _d + 4096 + sb); \
    GLOAD16(pB1, _d + 6144 + sb); \
    pA0 += 32; pA1 += 32; pB0 += 32; pB1 += 32; \
} while (0)

#define CLDS(tileoff, rb) (*(const f16x8*)&sm[cur + (tileoff) + (rb) * 512 + lr * 32 + lk * 8])

    f32x4 accH[3], accL[3];
#pragma unroll
    for (int ni = 0; ni < 3; ++ni) {
        accH[ni] = (f32x4){0.f, 0.f, 0.f, 0.f};
        accL[ni] = (f32x4){0.f, 0.f, 0.f, 0.f};
    }
    f16x8 av0, av1, bv0[3], bv1[3];

#define CCOMPUTE() do { \
    SBAR0(); \
    av0 = CLDS(0, wave); \
    av1 = CLDS(2048, wave); \
    _Pragma("unroll") for (int ni = 0; ni < 3; ++ni) bv0[ni] = CLDS(4096, ni); \
    _Pragma("unroll") for (int ni = 0; ni < 3; ++ni) bv1[ni] = CLDS(6144, ni); \
    asm volatile("s_waitcnt lgkmcnt(0)" ::: "memory"); \
    SBAR0(); \
    __builtin_amdgcn_s_barrier(); \
    SBAR0(); \
    _Pragma("unroll") for (int ni = 0; ni < 3; ++ni) \
        accH[ni] = __builtin_amdgcn_mfma_f32_16x16x32_f16(av0, bv0[ni], accH[ni], 0, 0, 0); \
    _Pragma("unroll") for (int ni = 0; ni < 3; ++ni) \
        accL[ni] = __builtin_amdgcn_mfma_f32_16x16x32_f16(av0, bv1[ni], accL[ni], 0, 0, 0); \
    _Pragma("unroll") for (int ni = 0; ni < 3; ++ni) \
        accL[ni] = __builtin_amdgcn_mfma_f32_16x16x32_f16(av1, bv0[ni], accL[ni], 0, 0, 0); \
} while (0)

    CSTAGE(0);
    for (int step = 0; step < 31; ++step) {
        const int cur = (step & 1) * 8192;
        CSTAGE((step + 1) & 1);
        SBAR0();
        asm volatile("s_waitcnt vmcnt(4)" ::: "memory");
        SBAR0();
        __builtin_amdgcn_s_barrier();
        CCOMPUTE();
    }
    {
        const int cur = 8192;
        SBAR0();
        asm volatile("s_waitcnt vmcnt(0)" ::: "memory");
        SBAR0();
        __builtin_amdgcn_s_barrier();
        CCOMPUTE();
    }

#pragma unroll
    for (int ni = 0; ni < 3; ++ni) {
        const int col = ni * 16 + lr;
        const float bvv = (col < 20) ? bc[col] : ((col < 40) ? ba[col - 20] : 0.f);
#pragma unroll
        for (int r = 0; r < 4; ++r) {
            const long row = bm + wave * 16 + lk * 4 + r;
            const float v = accH[ni][r] + SPLIT_INV * accL[ni][r] + bvv;
            if (col < 20)      clsx[row * CDIM + col] = v;
            else if (col < 40) atout[row * CDIM + col - 20] = v;
        }
    }
#undef CCOMPUTE
#undef CLDS
#undef CSTAGE
}

// ---------------------------------------------------------------------------
// Exact rank-KSEL: 4-pass radix-select, parallel digit scan.
// ---------------------------------------------------------------------------
__global__ __launch_bounds__(256)
void select_kth(const float* __restrict__ clsx_r, const float* __restrict__ clsx_f,
                float* __restrict__ kth) {
    __shared__ uint32_t su[TDIM];
    __shared__ uint32_t hist[256];
    __shared__ uint32_t sc[256];
    __shared__ uint32_t s_prefix, s_rank, s_mask;
    const int b = blockIdx.x;
    const int z = b / 640;
    const int rem = b - z * 640;
    const int n = rem / CDIM;
    const int c = rem - n * CDIM;
    const float* src = (z == 0) ? clsx_r : clsx_f;
    const int tid = threadIdx.x;

    for (int i = tid; i < TDIM; i += 256) {
        const uint32_t bits = __float_as_uint(src[((long)n * TDIM + i) * CDIM + c]);
        su[i] = (bits & 0x80000000u) ? ~bits : (bits | 0x80000000u);
    }
    if (tid == 0) { s_prefix = 0; s_rank = KSEL; s_mask = 0; }
    __syncthreads();

#pragma unroll
    for (int pass = 0; pass < 4; ++pass) {
        const int shift = 24 - pass * 8;
        hist[tid] = 0;
        __syncthreads();
        const uint32_t pfx = s_prefix, msk = s_mask, rk = s_rank;
        for (int i = tid; i < TDIM; i += 256) {
            const uint32_t u = su[i];
            if ((u & msk) == pfx) atomicAdd(&hist[(u >> shift) & 255u], 1u);
        }
        __syncthreads();
        sc[tid] = hist[tid];
        __syncthreads();
#pragma unroll
        for (int off = 1; off < 256; off <<= 1) {
            const uint32_t add = (tid >= off) ? sc[tid - off] : 0u;
            __syncthreads();
            sc[tid] += add;
            __syncthreads();
        }
        const uint32_t incl = sc[tid];
        const uint32_t excl = incl - hist[tid];
        if (excl < rk && incl >= rk) {
            s_prefix = pfx | ((uint32_t)tid << shift);
            s_rank   = rk - excl;
            s_mask   = msk | (0xffu << shift);
        }
        __syncthreads();
    }
    if (tid == 0) {
        const uint32_t u = s_prefix;
        kth[b] = (u & 0x80000000u) ? __uint_as_float(u ^ 0x80000000u)
                                   : __uint_as_float(~u);
    }
}

__global__ __launch_bounds__(256)
void final_mask(float* __restrict__ out, const float* __restrict__ kth,
                const float* __restrict__ mul_r, const float* __restrict__ mul_f) {
    const int idx = blockIdx.x * 256 + threadIdx.x;
    if (idx >= NBATCH * TDIM * CDIM) return;
    const int m = idx / CDIM;
    const int c = idx - m * CDIM;
    const int n = m / TDIM;
    const float xr  = out[OFF_CLSX_R + idx];
    const float xf  = out[OFF_CLSX_F + idx];
    const float atr = out[OFF_CLSRA + idx];
    const float atf = out[OFF_CLSFA + idx];
    const float kr = kth[n * CDIM + c];
    const float kf = kth[640 + n * CDIM + c];
    out[OFF_CLSRA + idx] = (xr > kr) ? MASKV : atr;
    out[OFF_CLSFA + idx] = (xf > kf) ? MASKV : atf;
    out[OFF_TCAM + idx]  = (xr + OMEGAF * atr) * mul_r[c] + (xf + OMEGAF * atf) * mul_f[c];
}

extern "C" void kernel_launch(void* const* d_in, const int* in_sizes, int n_in,
                              void* d_out, int out_size, void* d_ws, size_t ws_size,
                              hipStream_t stream) {
    const float* inp    = (const float*)d_in[0];
    const float* Wfc_r  = (const float*)d_in[1];
    const float* bfc_r  = (const float*)d_in[2];
    const float* Wfc1_r = (const float*)d_in[3];
    const float* bfc1_r = (const float*)d_in[4];
    const float* Wfc_f  = (const float*)d_in[5];
    const float* bfc_f  = (const float*)d_in[6];
    const float* Wfc1_f = (const float*)d_in[7];
    const float* bfc1_f = (const float*)d_in[8];
    const float* Wcls_r = (const float*)d_in[9];
    const float* bcls_r = (const float*)d_in[10];
    const float* Wcls_f = (const float*)d_in[11];
    const float* bcls_f = (const float*)d_in[12];
    const float* Wra    = (const float*)d_in[13];
    const float* bra    = (const float*)d_in[14];
    const float* Wfa    = (const float*)d_in[15];
    const float* bfa    = (const float*)d_in[16];
    const float* mul_r  = (const float*)d_in[17];
    const float* mul_f  = (const float*)d_in[18];

    float* out = (float*)d_out;
    _Float16* wsA0 = (_Float16*)d_ws;            // x splits (from layer-2 MODE2)
    _Float16* wsA1 = wsA0 + 24576000L;
    _Float16* wsH0 = wsA1 + 24576000L;
    _Float16* wsH1 = wsH0 + 24576000L;
    _Float16* wsW  = wsH1 + 24576000L;           // 8 x 1024x1024 f16
    _Float16* wsWc = wsW + 8L * 1048576L;        // 4 x 64x1024 f16 (cls W splits)
    float* kth = (float*)(wsWc + 4L * 65536L);   // 1280 f32

    dim3 blk(256);
    dim3 gg(1504);

    split_w4<<<dim3(2048), blk, 0, stream>>>(Wfc_r, Wfc1_r, Wfc_f, Wfc1_f, wsW);
    split_clsW2<<<dim3(512), blk, 0, stream>>>(Wcls_r, Wra, Wcls_f, Wfa, wsWc);

    // ---- RGB stream ----
    gemm_l1_f32a<<<gg, blk, 0, stream>>>(inp, wsW + 0L * 1048576, wsW + 1L * 1048576,
                                         bfc_r, wsH0, wsH1);
    gemm_fused_f16<2><<<gg, blk, 0, stream>>>(wsH0, wsH1, wsW + 2L * 1048576, wsW + 3L * 1048576,
                                              bfc1_r, out + OFF_XR, wsA0, wsA1);
    cls_mfma_f16<<<dim3(375), blk, 0, stream>>>(wsA0, wsA1, wsWc + 0L * 65536, wsWc + 1L * 65536,
                                                bcls_r, bra, out + OFF_CLSX_R, out + OFF_CLSRA);

    // ---- Flow stream ----
    gemm_l1_f32a<<<gg, blk, 0, stream>>>(inp + DDIM, wsW + 4L * 1048576, wsW + 5L * 1048576,
                                         bfc_f, wsH0, wsH1);
    gemm_fused_f16<2><<<gg, blk, 0, stream>>>(wsH0, wsH1, wsW + 6L * 1048576, wsW + 7L * 1048576,
                                              bfc1_f, out + OFF_XF, wsA0, wsA1);
    cls_mfma_f16<<<dim3(375), blk, 0, stream>>>(wsA0, wsA1, wsWc + 2L * 65536, wsWc + 3L * 65536,
                                                bcls_f, bfa, out + OFF_CLSX_F, out + OFF_CLSFA);

    select_kth<<<dim3(1280), blk, 0, stream>>>(out + OFF_CLSX_R, out + OFF_CLSX_F, kth);
    final_mask<<<dim3((NBATCH * TDIM * CDIM + 255) / 256), blk, 0, stream>>>(out, kth, mul_r, mul_f);
}